// Round 1
// baseline (4063.348 us; speedup 1.0000x reference)
//
#include <hip/hip_runtime.h>

#define N_ENT  100000
#define EHALF  500000
#define NE2    1000000
#define D      256
#define NREL   200
#define BN_EPS 1e-5f

// ---------------- degree ----------------
__global__ void degree_kernel(const int* __restrict__ ei, float* __restrict__ deg_in,
                              float* __restrict__ deg_out) {
    int e = blockIdx.x * blockDim.x + threadIdx.x;
    if (e >= NE2) return;
    int row = ei[e];
    if (e < EHALF) atomicAdd(&deg_in[row], 1.0f);
    else           atomicAdd(&deg_out[row], 1.0f);
}

__global__ void deginv_kernel(float* __restrict__ deg) {
    int i = blockIdx.x * blockDim.x + threadIdx.x;
    if (i >= 2 * N_ENT) return;
    float d = deg[i];
    deg[i] = d > 0.0f ? rsqrtf(d) : 0.0f;
}

// ---------------- edge aggregation (one wave per edge) ----------------
__global__ __launch_bounds__(256) void aggregate_kernel(
        const int* __restrict__ ei, const int* __restrict__ et,
        const float* __restrict__ x, const float* __restrict__ rel,
        const float* __restrict__ dinv, float* __restrict__ agg, int base) {
    int wid  = (blockIdx.x * blockDim.x + threadIdx.x) >> 6;
    int lane = threadIdx.x & 63;
    if (wid >= EHALF) return;
    int e   = base + wid;
    int row = ei[e];
    int col = ei[NE2 + e];
    int t   = et[e];
    float s = dinv[row] * dinv[col];
    float4 xv = *(const float4*)(x   + (size_t)col * D + lane * 4);
    float4 rv = *(const float4*)(rel + (size_t)t   * D + lane * 4);
    float* dst = agg + (size_t)row * D + lane * 4;
    atomicAdd(dst + 0, xv.x * rv.x * s);
    atomicAdd(dst + 1, xv.y * rv.y * s);
    atomicAdd(dst + 2, xv.z * rv.z * s);
    atomicAdd(dst + 3, xv.w * rv.w * s);
}

// ---------------- f32 tiled GEMM: C[M x 256] (+)= (A .* colscale) @ W ----------------
template<bool ACC, bool COLSCALE>
__global__ __launch_bounds__(256) void gemm_kernel(
        const float* __restrict__ A, const float* __restrict__ W,
        const float* __restrict__ colscale, float* __restrict__ C, int M) {
    __shared__ float As[16][68];   // k-major, padded
    __shared__ float Bs[16][64];
    int tid  = threadIdx.x;
    int row0 = blockIdx.x * 64;
    int col0 = blockIdx.y * 64;
    int tx = tid & 15, ty = tid >> 4;
    float acc[4][4] = {};

    int lr  = tid >> 2;          // 0..63 : A-tile row
    int lc4 = (tid & 3) * 4;     // 0,4,8,12 : A-tile k offset
    int wr  = tid >> 4;          // 0..15 : W-tile k row
    int wc4 = (tid & 15) * 4;    // 0..60 : W-tile col offset

    for (int k0 = 0; k0 < 256; k0 += 16) {
        float4 av = make_float4(0.f, 0.f, 0.f, 0.f);
        int ar = row0 + lr;
        if (ar < M) av = *(const float4*)(A + (size_t)ar * 256 + k0 + lc4);
        if (COLSCALE) {
            float4 cs = *(const float4*)(colscale + k0 + lc4);
            av.x *= cs.x; av.y *= cs.y; av.z *= cs.z; av.w *= cs.w;
        }
        As[lc4 + 0][lr] = av.x;
        As[lc4 + 1][lr] = av.y;
        As[lc4 + 2][lr] = av.z;
        As[lc4 + 3][lr] = av.w;
        *(float4*)&Bs[wr][wc4] = *(const float4*)(W + (size_t)(k0 + wr) * 256 + col0 + wc4);
        __syncthreads();
#pragma unroll
        for (int k = 0; k < 16; ++k) {
            float4 a4 = *(const float4*)&As[k][ty * 4];
            float4 b4 = *(const float4*)&Bs[k][tx * 4];
            float a[4] = {a4.x, a4.y, a4.z, a4.w};
            float b[4] = {b4.x, b4.y, b4.z, b4.w};
#pragma unroll
            for (int i = 0; i < 4; ++i)
#pragma unroll
                for (int j = 0; j < 4; ++j)
                    acc[i][j] = fmaf(a[i], b[j], acc[i][j]);
        }
        __syncthreads();
    }
#pragma unroll
    for (int i = 0; i < 4; ++i) {
        int r = row0 + ty * 4 + i;
        if (r >= M) continue;
#pragma unroll
        for (int j = 0; j < 4; ++j) {
            size_t o = (size_t)r * 256 + col0 + tx * 4 + j;
            C[o] = ACC ? C[o] + acc[i][j] : acc[i][j];
        }
    }
}

// ---------------- BatchNorm ----------------
__global__ __launch_bounds__(256) void bn_stats_kernel(
        const float* __restrict__ out, const float* __restrict__ bias,
        float* __restrict__ colsum, float* __restrict__ colsumsq) {
    int c  = threadIdx.x;
    int r0 = blockIdx.x * 64;
    float b = bias[c];
    float s = 0.f, sq = 0.f;
    int rend = min(r0 + 64, N_ENT);
    for (int r = r0; r < rend; ++r) {
        float v = out[(size_t)r * 256 + c] * (1.f / 3.f) + b;
        s += v; sq += v * v;
    }
    atomicAdd(&colsum[c], s);
    atomicAdd(&colsumsq[c], sq);
}

__global__ void bn_finalize_kernel(const float* __restrict__ colsum, const float* __restrict__ colsumsq,
                                   const float* __restrict__ bias, const float* __restrict__ gamma,
                                   const float* __restrict__ beta,
                                   float* __restrict__ colA, float* __restrict__ colB) {
    int c = threadIdx.x;
    float mean = colsum[c] * (1.f / N_ENT);
    float var  = colsumsq[c] * (1.f / N_ENT) - mean * mean;
    float sc   = rsqrtf(var + BN_EPS) * gamma[c];
    colA[c] = sc * (1.f / 3.f);
    colB[c] = (bias[c] - mean) * sc + beta[c];
}

__global__ __launch_bounds__(256) void bn_apply_kernel(
        float* __restrict__ out, const float* __restrict__ colA, const float* __restrict__ colB) {
    size_t i4 = (size_t)blockIdx.x * 256 + threadIdx.x;   // over N_ENT*64 float4s
    float4 v = ((const float4*)out)[i4];
    int c4 = (int)(i4 & 63) * 4;
    v.x = v.x * colA[c4 + 0] + colB[c4 + 0];
    v.y = v.y * colA[c4 + 1] + colB[c4 + 1];
    v.z = v.z * colA[c4 + 2] + colB[c4 + 2];
    v.w = v.w * colA[c4 + 3] + colB[c4 + 3];
    ((float4*)out)[i4] = v;
}

// ---------------- rel_out = rel_embed @ w_rel ----------------
__global__ __launch_bounds__(256) void relgemm_kernel(
        const float* __restrict__ rel, const float* __restrict__ w, float* __restrict__ out) {
    int r = blockIdx.x;
    int c = threadIdx.x;
    float acc = 0.f;
    for (int k = 0; k < 256; ++k)
        acc = fmaf(rel[r * 256 + k], w[k * 256 + c], acc);
    out[r * 256 + c] = acc;
}

extern "C" void kernel_launch(void* const* d_in, const int* in_sizes, int n_in,
                              void* d_out, int out_size, void* d_ws, size_t ws_size,
                              hipStream_t stream) {
    const float* x        = (const float*)d_in[0];
    const int*   ei       = (const int*)d_in[1];
    const int*   et       = (const int*)d_in[2];
    const float* rel      = (const float*)d_in[3];
    const float* w_loop   = (const float*)d_in[4];
    const float* w_in     = (const float*)d_in[5];
    const float* w_out    = (const float*)d_in[6];
    const float* w_rel    = (const float*)d_in[7];
    const float* loop_rel = (const float*)d_in[8];
    const float* bias     = (const float*)d_in[9];
    const float* gamma    = (const float*)d_in[10];
    const float* beta     = (const float*)d_in[11];

    float* out     = (float*)d_out;                  // N_ENT*D
    float* rel_out = out + (size_t)N_ENT * D;        // NREL*D

    char*  ws      = (char*)d_ws;
    float* agg     = (float*)ws;                               // N_ENT*D floats
    float* deg     = (float*)(ws + (size_t)N_ENT * D * 4);     // 2*N_ENT (becomes deg_inv in place)
    float* deg_in  = deg;
    float* deg_out = deg + N_ENT;
    float* stats   = deg + 2 * N_ENT;                          // 1024 floats
    float* colsum  = stats, *colsumsq = stats + 256;
    float* colA    = stats + 512, *colB = stats + 768;

    // zero degree + stats
    hipMemsetAsync(deg, 0, (size_t)(2 * N_ENT + 1024) * 4, stream);
    degree_kernel<<<(NE2 + 255) / 256, 256, 0, stream>>>(ei, deg_in, deg_out);
    deginv_kernel<<<(2 * N_ENT + 255) / 256, 256, 0, stream>>>(deg);

    dim3 ggrid((N_ENT + 63) / 64, 4);

    // in-half
    hipMemsetAsync(agg, 0, (size_t)N_ENT * D * 4, stream);
    aggregate_kernel<<<EHALF / 4, 256, 0, stream>>>(ei, et, x, rel, deg_in, agg, 0);
    gemm_kernel<false, false><<<ggrid, 256, 0, stream>>>(agg, w_in, nullptr, out, N_ENT);

    // out-half
    hipMemsetAsync(agg, 0, (size_t)N_ENT * D * 4, stream);
    aggregate_kernel<<<EHALF / 4, 256, 0, stream>>>(ei, et, x, rel, deg_out, agg, EHALF);
    gemm_kernel<true, false><<<ggrid, 256, 0, stream>>>(agg, w_out, nullptr, out, N_ENT);

    // loop term
    gemm_kernel<true, true><<<ggrid, 256, 0, stream>>>(x, w_loop, loop_rel, out, N_ENT);

    // batchnorm
    bn_stats_kernel<<<(N_ENT + 63) / 64, 256, 0, stream>>>(out, bias, colsum, colsumsq);
    bn_finalize_kernel<<<1, 256, 0, stream>>>(colsum, colsumsq, bias, gamma, beta, colA, colB);
    bn_apply_kernel<<<(N_ENT * 64) / 256, 256, 0, stream>>>(out, colA, colB);

    // relation output
    relgemm_kernel<<<NREL, 256, 0, stream>>>(rel, w_rel, rel_out);
}

// Round 2
// 1156.838 us; speedup vs baseline: 3.5125x; 3.5125x over previous
//
#include <hip/hip_runtime.h>

#define N_ENT  100000
#define EHALF  500000
#define NE2    1000000
#define D      256
#define NREL   200
#define BN_EPS 1e-5f

// ================= CSR build =================
__global__ __launch_bounds__(256) void hist_kernel(const int* __restrict__ ei,
                                                   int* __restrict__ cnt_in,
                                                   int* __restrict__ cnt_out) {
    int e = blockIdx.x * blockDim.x + threadIdx.x;
    if (e >= NE2) return;
    int row = ei[e];
    if (e < EHALF) atomicAdd(&cnt_in[row], 1);
    else           atomicAdd(&cnt_out[row], 1);
}

// one block per half: exclusive scan of cnt -> rp (and cursor copy in cnt), dinv = rsqrt(cnt)
__global__ __launch_bounds__(1024) void scan_kernel(int* __restrict__ cnt_in, int* __restrict__ rp_in,
                                                    float* __restrict__ dv_in,
                                                    int* __restrict__ cnt_out, int* __restrict__ rp_out,
                                                    float* __restrict__ dv_out) {
    int*   cnt = blockIdx.x ? cnt_out : cnt_in;
    int*   rp  = blockIdx.x ? rp_out  : rp_in;
    float* dv  = blockIdx.x ? dv_out  : dv_in;
    __shared__ int sm[1024];
    int tid = threadIdx.x;
    int carry = 0;
    for (int base = 0; base < N_ENT; base += 1024) {
        int i = base + tid;
        int v = (i < N_ENT) ? cnt[i] : 0;
        if (i < N_ENT) dv[i] = v > 0 ? rsqrtf((float)v) : 0.0f;
        sm[tid] = v;
        __syncthreads();
        for (int off = 1; off < 1024; off <<= 1) {
            int t = 0;
            if (tid >= off) t = sm[tid - off];
            __syncthreads();
            sm[tid] += t;
            __syncthreads();
        }
        int incl = sm[tid];
        int excl = incl - v + carry;
        if (i < N_ENT) { rp[i] = excl; cnt[i] = excl; }   // cnt becomes cursor
        carry += sm[1023];
        __syncthreads();
    }
    if (tid == 0) rp[N_ENT] = carry;
}

__global__ __launch_bounds__(256) void scatter_kernel(const int* __restrict__ ei,
                                                      int* __restrict__ cur_in, int* __restrict__ cur_out,
                                                      int* __restrict__ el_in, int* __restrict__ el_out) {
    int e = blockIdx.x * blockDim.x + threadIdx.x;
    if (e >= NE2) return;
    int row = ei[e];
    if (e < EHALF) { int p = atomicAdd(&cur_in[row], 1);  el_in[p]  = e; }
    else           { int p = atomicAdd(&cur_out[row], 1); el_out[p] = e; }
}

// ============ gather-style aggregation: one wave per entity ============
__global__ __launch_bounds__(256) void agg_csr_kernel(
        const int* __restrict__ rp, const int* __restrict__ elist,
        const int* __restrict__ colidx, const int* __restrict__ et,
        const float* __restrict__ dinv, const float* __restrict__ x,
        const float* __restrict__ rel, float* __restrict__ agg) {
    int wid  = (blockIdx.x * blockDim.x + threadIdx.x) >> 6;   // entity
    int lane = threadIdx.x & 63;
    if (wid >= N_ENT) return;
    int s = rp[wid], eend = rp[wid + 1];
    float dr = dinv[wid];
    float4 acc = make_float4(0.f, 0.f, 0.f, 0.f);
    int e = (s < eend) ? elist[s] : 0;
    for (int p = s; p < eend; ++p) {
        int c = colidx[e];
        int t = et[e];
        int enext = (p + 1 < eend) ? elist[p + 1] : 0;
        float sc = dr * dinv[c];
        float4 xv = *(const float4*)(x   + (size_t)c * D + lane * 4);
        float4 rv = *(const float4*)(rel + (size_t)t * D + lane * 4);
        acc.x = fmaf(xv.x * rv.x, sc, acc.x);
        acc.y = fmaf(xv.y * rv.y, sc, acc.y);
        acc.z = fmaf(xv.z * rv.z, sc, acc.z);
        acc.w = fmaf(xv.w * rv.w, sc, acc.w);
        e = enext;
    }
    *(float4*)(agg + (size_t)wid * D + lane * 4) = acc;
}

// ============ fallback: atomic aggregation (if ws too small) ============
__global__ void degree_kernel(const int* __restrict__ ei, float* __restrict__ deg_in,
                              float* __restrict__ deg_out) {
    int e = blockIdx.x * blockDim.x + threadIdx.x;
    if (e >= NE2) return;
    int row = ei[e];
    if (e < EHALF) atomicAdd(&deg_in[row], 1.0f);
    else           atomicAdd(&deg_out[row], 1.0f);
}

__global__ void deginv_kernel(float* __restrict__ deg) {
    int i = blockIdx.x * blockDim.x + threadIdx.x;
    if (i >= 2 * N_ENT) return;
    float d = deg[i];
    deg[i] = d > 0.0f ? rsqrtf(d) : 0.0f;
}

__global__ __launch_bounds__(256) void aggregate_kernel(
        const int* __restrict__ ei, const int* __restrict__ et,
        const float* __restrict__ x, const float* __restrict__ rel,
        const float* __restrict__ dinv, float* __restrict__ agg, int base) {
    int wid  = (blockIdx.x * blockDim.x + threadIdx.x) >> 6;
    int lane = threadIdx.x & 63;
    if (wid >= EHALF) return;
    int e   = base + wid;
    int row = ei[e];
    int col = ei[NE2 + e];
    int t   = et[e];
    float s = dinv[row] * dinv[col];
    float4 xv = *(const float4*)(x   + (size_t)col * D + lane * 4);
    float4 rv = *(const float4*)(rel + (size_t)t   * D + lane * 4);
    float* dst = agg + (size_t)row * D + lane * 4;
    atomicAdd(dst + 0, xv.x * rv.x * s);
    atomicAdd(dst + 1, xv.y * rv.y * s);
    atomicAdd(dst + 2, xv.z * rv.z * s);
    atomicAdd(dst + 3, xv.w * rv.w * s);
}

// ---------------- f32 tiled GEMM: C[M x 256] (+)= (A .* colscale) @ W ----------------
template<bool ACC, bool COLSCALE>
__global__ __launch_bounds__(256) void gemm_kernel(
        const float* __restrict__ A, const float* __restrict__ W,
        const float* __restrict__ colscale, float* __restrict__ C, int M) {
    __shared__ float As[16][68];   // k-major, padded
    __shared__ float Bs[16][64];
    int tid  = threadIdx.x;
    int row0 = blockIdx.x * 64;
    int col0 = blockIdx.y * 64;
    int tx = tid & 15, ty = tid >> 4;
    float acc[4][4] = {};

    int lr  = tid >> 2;          // 0..63 : A-tile row
    int lc4 = (tid & 3) * 4;     // 0,4,8,12 : A-tile k offset
    int wr  = tid >> 4;          // 0..15 : W-tile k row
    int wc4 = (tid & 15) * 4;    // 0..60 : W-tile col offset

    for (int k0 = 0; k0 < 256; k0 += 16) {
        float4 av = make_float4(0.f, 0.f, 0.f, 0.f);
        int ar = row0 + lr;
        if (ar < M) av = *(const float4*)(A + (size_t)ar * 256 + k0 + lc4);
        if (COLSCALE) {
            float4 cs = *(const float4*)(colscale + k0 + lc4);
            av.x *= cs.x; av.y *= cs.y; av.z *= cs.z; av.w *= cs.w;
        }
        As[lc4 + 0][lr] = av.x;
        As[lc4 + 1][lr] = av.y;
        As[lc4 + 2][lr] = av.z;
        As[lc4 + 3][lr] = av.w;
        *(float4*)&Bs[wr][wc4] = *(const float4*)(W + (size_t)(k0 + wr) * 256 + col0 + wc4);
        __syncthreads();
#pragma unroll
        for (int k = 0; k < 16; ++k) {
            float4 a4 = *(const float4*)&As[k][ty * 4];
            float4 b4 = *(const float4*)&Bs[k][tx * 4];
            float a[4] = {a4.x, a4.y, a4.z, a4.w};
            float b[4] = {b4.x, b4.y, b4.z, b4.w};
#pragma unroll
            for (int i = 0; i < 4; ++i)
#pragma unroll
                for (int j = 0; j < 4; ++j)
                    acc[i][j] = fmaf(a[i], b[j], acc[i][j]);
        }
        __syncthreads();
    }
#pragma unroll
    for (int i = 0; i < 4; ++i) {
        int r = row0 + ty * 4 + i;
        if (r >= M) continue;
#pragma unroll
        for (int j = 0; j < 4; ++j) {
            size_t o = (size_t)r * 256 + col0 + tx * 4 + j;
            C[o] = ACC ? C[o] + acc[i][j] : acc[i][j];
        }
    }
}

// ---------------- BatchNorm ----------------
__global__ __launch_bounds__(256) void bn_stats_kernel(
        const float* __restrict__ out, const float* __restrict__ bias,
        float* __restrict__ colsum, float* __restrict__ colsumsq) {
    int c  = threadIdx.x;
    int r0 = blockIdx.x * 64;
    float b = bias[c];
    float s = 0.f, sq = 0.f;
    int rend = min(r0 + 64, N_ENT);
    for (int r = r0; r < rend; ++r) {
        float v = out[(size_t)r * 256 + c] * (1.f / 3.f) + b;
        s += v; sq += v * v;
    }
    atomicAdd(&colsum[c], s);
    atomicAdd(&colsumsq[c], sq);
}

__global__ void bn_finalize_kernel(const float* __restrict__ colsum, const float* __restrict__ colsumsq,
                                   const float* __restrict__ bias, const float* __restrict__ gamma,
                                   const float* __restrict__ beta,
                                   float* __restrict__ colA, float* __restrict__ colB) {
    int c = threadIdx.x;
    float mean = colsum[c] * (1.f / N_ENT);
    float var  = colsumsq[c] * (1.f / N_ENT) - mean * mean;
    float sc   = rsqrtf(var + BN_EPS) * gamma[c];
    colA[c] = sc * (1.f / 3.f);
    colB[c] = (bias[c] - mean) * sc + beta[c];
}

__global__ __launch_bounds__(256) void bn_apply_kernel(
        float* __restrict__ out, const float* __restrict__ colA, const float* __restrict__ colB) {
    size_t i4 = (size_t)blockIdx.x * 256 + threadIdx.x;   // over N_ENT*64 float4s
    float4 v = ((const float4*)out)[i4];
    int c4 = (int)(i4 & 63) * 4;
    v.x = v.x * colA[c4 + 0] + colB[c4 + 0];
    v.y = v.y * colA[c4 + 1] + colB[c4 + 1];
    v.z = v.z * colA[c4 + 2] + colB[c4 + 2];
    v.w = v.w * colA[c4 + 3] + colB[c4 + 3];
    ((float4*)out)[i4] = v;
}

// ---------------- rel_out = rel_embed @ w_rel ----------------
__global__ __launch_bounds__(256) void relgemm_kernel(
        const float* __restrict__ rel, const float* __restrict__ w, float* __restrict__ out) {
    int r = blockIdx.x;
    int c = threadIdx.x;
    float acc = 0.f;
    for (int k = 0; k < 256; ++k)
        acc = fmaf(rel[r * 256 + k], w[k * 256 + c], acc);
    out[r * 256 + c] = acc;
}

extern "C" void kernel_launch(void* const* d_in, const int* in_sizes, int n_in,
                              void* d_out, int out_size, void* d_ws, size_t ws_size,
                              hipStream_t stream) {
    const float* x        = (const float*)d_in[0];
    const int*   ei       = (const int*)d_in[1];
    const int*   et       = (const int*)d_in[2];
    const float* rel      = (const float*)d_in[3];
    const float* w_loop   = (const float*)d_in[4];
    const float* w_in     = (const float*)d_in[5];
    const float* w_out    = (const float*)d_in[6];
    const float* w_rel    = (const float*)d_in[7];
    const float* loop_rel = (const float*)d_in[8];
    const float* bias     = (const float*)d_in[9];
    const float* gamma    = (const float*)d_in[10];
    const float* beta     = (const float*)d_in[11];

    float* out     = (float*)d_out;                  // N_ENT*D
    float* rel_out = out + (size_t)N_ENT * D;        // NREL*D

    // ---- workspace layout ----
    char*  ws = (char*)d_ws;
    size_t off = 0;
    float* agg = (float*)(ws + off);          off += (size_t)N_ENT * D * 4;   // 102.4 MB
    float* stats = (float*)(ws + off);        off += 1024 * 4;
    float* colsum = stats, *colsumsq = stats + 256;
    float* colA = stats + 512, *colB = stats + 768;
    int* cnt_in  = (int*)(ws + off);          off += (size_t)N_ENT * 4;
    int* cnt_out = (int*)(ws + off);          off += (size_t)N_ENT * 4;
    int* rp_in   = (int*)(ws + off);          off += (size_t)(N_ENT + 1) * 4;
    int* rp_out  = (int*)(ws + off);          off += (size_t)(N_ENT + 1) * 4;
    float* dv_in  = (float*)(ws + off);       off += (size_t)N_ENT * 4;
    float* dv_out = (float*)(ws + off);       off += (size_t)N_ENT * 4;
    int* el_in   = (int*)(ws + off);          off += (size_t)EHALF * 4;
    int* el_out  = (int*)(ws + off);          off += (size_t)EHALF * 4;
    size_t needed_csr = off;

    dim3 ggrid((N_ENT + 63) / 64, 4);
    const int* colidx = ei + NE2;

    if (ws_size >= needed_csr) {
        // ======== CSR path ========
        hipMemsetAsync(cnt_in, 0, (size_t)2 * N_ENT * 4, stream);
        hipMemsetAsync(stats, 0, 1024 * 4, stream);
        hist_kernel<<<(NE2 + 255) / 256, 256, 0, stream>>>(ei, cnt_in, cnt_out);
        scan_kernel<<<2, 1024, 0, stream>>>(cnt_in, rp_in, dv_in, cnt_out, rp_out, dv_out);
        scatter_kernel<<<(NE2 + 255) / 256, 256, 0, stream>>>(ei, cnt_in, cnt_out, el_in, el_out);

        agg_csr_kernel<<<(N_ENT * 64 + 255) / 256, 256, 0, stream>>>(
            rp_in, el_in, colidx, et, dv_in, x, rel, agg);
        gemm_kernel<false, false><<<ggrid, 256, 0, stream>>>(agg, w_in, nullptr, out, N_ENT);

        agg_csr_kernel<<<(N_ENT * 64 + 255) / 256, 256, 0, stream>>>(
            rp_out, el_out, colidx, et, dv_out, x, rel, agg);
        gemm_kernel<true, false><<<ggrid, 256, 0, stream>>>(agg, w_out, nullptr, out, N_ENT);
    } else {
        // ======== fallback: atomic path ========
        float* deg    = (float*)cnt_in;   // 2*N_ENT floats
        float* deg_in = deg;
        float* deg_out = deg + N_ENT;
        hipMemsetAsync(deg, 0, (size_t)2 * N_ENT * 4, stream);
        hipMemsetAsync(stats, 0, 1024 * 4, stream);
        degree_kernel<<<(NE2 + 255) / 256, 256, 0, stream>>>(ei, deg_in, deg_out);
        deginv_kernel<<<(2 * N_ENT + 255) / 256, 256, 0, stream>>>(deg);

        hipMemsetAsync(agg, 0, (size_t)N_ENT * D * 4, stream);
        aggregate_kernel<<<EHALF / 4, 256, 0, stream>>>(ei, et, x, rel, deg_in, agg, 0);
        gemm_kernel<false, false><<<ggrid, 256, 0, stream>>>(agg, w_in, nullptr, out, N_ENT);

        hipMemsetAsync(agg, 0, (size_t)N_ENT * D * 4, stream);
        aggregate_kernel<<<EHALF / 4, 256, 0, stream>>>(ei, et, x, rel, deg_out, agg, EHALF);
        gemm_kernel<true, false><<<ggrid, 256, 0, stream>>>(agg, w_out, nullptr, out, N_ENT);
    }

    // loop term
    gemm_kernel<true, true><<<ggrid, 256, 0, stream>>>(x, w_loop, loop_rel, out, N_ENT);

    // batchnorm
    bn_stats_kernel<<<(N_ENT + 63) / 64, 256, 0, stream>>>(out, bias, colsum, colsumsq);
    bn_finalize_kernel<<<1, 256, 0, stream>>>(colsum, colsumsq, bias, gamma, beta, colA, colB);
    bn_apply_kernel<<<(N_ENT * 64) / 256, 256, 0, stream>>>(out, colA, colB);

    // relation output
    relgemm_kernel<<<NREL, 256, 0, stream>>>(rel, w_rel, rel_out);
}

// Round 3
// 551.650 us; speedup vs baseline: 7.3658x; 2.0971x over previous
//
#include <hip/hip_runtime.h>

#define N_ENT  100000
#define MPAD   100096           // 782 * 128
#define EHALF  500000
#define NE2    1000000
#define D      256
#define NREL   200
#define BN_EPS 1e-5f

typedef __attribute__((ext_vector_type(8))) short  bf16x8;
typedef __attribute__((ext_vector_type(8))) ushort us8;
typedef __attribute__((ext_vector_type(4))) float  f32x4;

__device__ __forceinline__ ushort f2b(float f) {
    unsigned u = __float_as_uint(f);
    return (ushort)((u + 0x7fffu + ((u >> 16) & 1u)) >> 16);
}

// ================= CSR build =================
__global__ __launch_bounds__(256) void hist_kernel(const int* __restrict__ ei,
                                                   int* __restrict__ cnt_in,
                                                   int* __restrict__ cnt_out) {
    int e = blockIdx.x * blockDim.x + threadIdx.x;
    if (e >= NE2) return;
    int row = ei[e];
    if (e < EHALF) atomicAdd(&cnt_in[row], 1);
    else           atomicAdd(&cnt_out[row], 1);
}

// phase 1: per-block local exclusive scan + block sums; also dinv
__global__ __launch_bounds__(256) void scan1_kernel(const int* __restrict__ cnt_in,
                                                    const int* __restrict__ cnt_out,
                                                    int* __restrict__ rp_in, int* __restrict__ rp_out,
                                                    float* __restrict__ dv_in, float* __restrict__ dv_out,
                                                    int* __restrict__ bsum) {
    int half = blockIdx.y;
    const int* cnt = half ? cnt_out : cnt_in;
    int* rp  = half ? rp_out : rp_in;
    float* dv = half ? dv_out : dv_in;
    __shared__ int sm[256];
    int tid = threadIdx.x;
    int base = blockIdx.x * 1024 + tid * 4;
    int v[4];
#pragma unroll
    for (int j = 0; j < 4; ++j) { int i = base + j; v[j] = (i < N_ENT) ? cnt[i] : 0; }
    int tsum = v[0] + v[1] + v[2] + v[3];
    sm[tid] = tsum;
    __syncthreads();
    for (int off = 1; off < 256; off <<= 1) {
        int t = (tid >= off) ? sm[tid - off] : 0;
        __syncthreads();
        sm[tid] += t;
        __syncthreads();
    }
    int run = sm[tid] - tsum;
#pragma unroll
    for (int j = 0; j < 4; ++j) {
        int i = base + j;
        if (i < N_ENT) {
            rp[i] = run;
            dv[i] = v[j] > 0 ? rsqrtf((float)v[j]) : 0.0f;
        }
        run += v[j];
    }
    if (tid == 255) bsum[half * 98 + blockIdx.x] = sm[255];
}

// phase 2: serial scan of 98 block sums per half (2 threads)
__global__ void scan2_kernel(int* __restrict__ bsum) {
    int h = threadIdx.x;
    if (h >= 2) return;
    int run = 0;
    for (int b = 0; b < 98; ++b) { int t = bsum[h * 98 + b]; bsum[h * 98 + b] = run; run += t; }
}

// phase 3: add block offsets; copy to cursor; rp[N]=EHALF
__global__ __launch_bounds__(256) void scan3_kernel(int* __restrict__ rp_in, int* __restrict__ rp_out,
                                                    int* __restrict__ cnt_in, int* __restrict__ cnt_out,
                                                    const int* __restrict__ bsum) {
    int half = blockIdx.y;
    int* rp  = half ? rp_out : rp_in;
    int* cnt = half ? cnt_out : cnt_in;
    int add = bsum[half * 98 + blockIdx.x];
    int base = blockIdx.x * 1024 + threadIdx.x * 4;
#pragma unroll
    for (int j = 0; j < 4; ++j) {
        int i = base + j;
        if (i < N_ENT) { int t = rp[i] + add; rp[i] = t; cnt[i] = t; }
    }
    if (blockIdx.x == 0 && threadIdx.x == 0) rp[N_ENT] = EHALF;
}

__global__ __launch_bounds__(256) void scatter_kernel(const int* __restrict__ ei,
                                                      int* __restrict__ cur_in, int* __restrict__ cur_out,
                                                      int* __restrict__ el_in, int* __restrict__ el_out) {
    int e = blockIdx.x * blockDim.x + threadIdx.x;
    if (e >= NE2) return;
    int row = ei[e];
    if (e < EHALF) { int p = atomicAdd(&cur_in[row], 1);  el_in[p]  = e; }
    else           { int p = atomicAdd(&cur_out[row], 1); el_out[p] = e; }
}

// ============ gather aggregation -> bf16 (one wave per entity) ============
__global__ __launch_bounds__(256) void agg_csr16_kernel(
        const int* __restrict__ rp, const int* __restrict__ elist,
        const int* __restrict__ colidx, const int* __restrict__ et,
        const float* __restrict__ dinv, const float* __restrict__ x,
        const float* __restrict__ rel, ushort* __restrict__ agg) {
    int wid  = (blockIdx.x * blockDim.x + threadIdx.x) >> 6;
    int lane = threadIdx.x & 63;
    if (wid >= N_ENT) return;
    int s = rp[wid], eend = rp[wid + 1];
    float dr = dinv[wid];
    float4 acc = make_float4(0.f, 0.f, 0.f, 0.f);
    int e = (s < eend) ? elist[s] : 0;
    for (int p = s; p < eend; ++p) {
        int c = colidx[e];
        int t = et[e];
        int enext = (p + 1 < eend) ? elist[p + 1] : 0;
        float sc = dr * dinv[c];
        float4 xv = *(const float4*)(x   + (size_t)c * D + lane * 4);
        float4 rv = *(const float4*)(rel + (size_t)t * D + lane * 4);
        acc.x = fmaf(xv.x * rv.x, sc, acc.x);
        acc.y = fmaf(xv.y * rv.y, sc, acc.y);
        acc.z = fmaf(xv.z * rv.z, sc, acc.z);
        acc.w = fmaf(xv.w * rv.w, sc, acc.w);
        e = enext;
    }
    ushort4 o;
    o.x = f2b(acc.x); o.y = f2b(acc.y); o.z = f2b(acc.z); o.w = f2b(acc.w);
    *(ushort4*)(agg + (size_t)wid * D + lane * 4) = o;
}

// ============ weight transpose -> bf16: wT[n][k], k in [0,768) ============
__global__ __launch_bounds__(256) void wconv_kernel(const float* __restrict__ w_in,
                                                    const float* __restrict__ w_out,
                                                    const float* __restrict__ w_loop,
                                                    ushort* __restrict__ wT) {
    int n = blockIdx.x;
    int k = threadIdx.x;
    wT[(size_t)n * 768 + 0   + k] = f2b(w_in  [k * 256 + n]);
    wT[(size_t)n * 768 + 256 + k] = f2b(w_out [k * 256 + n]);
    wT[(size_t)n * 768 + 512 + k] = f2b(w_loop[k * 256 + n]);
}

// ============ fused bf16 MFMA GEMM: C = [Ain|Aout|x.*lrel] @ wT^T ============
// tile 128x128, BK=32, 4 waves (each 64x64), double-buffered LDS, row pad +8
__global__ __launch_bounds__(256) void fused_gemm_kernel(
        const ushort* __restrict__ Ain, const ushort* __restrict__ Aout,
        const float* __restrict__ x, const float* __restrict__ lrel,
        const ushort* __restrict__ wT, float* __restrict__ C) {
    __shared__ ushort As[2][128 * 40];
    __shared__ ushort Bs[2][128 * 40];
    int tid  = threadIdx.x;
    int row0 = blockIdx.x * 128;
    int col0 = blockIdx.y * 128;
    int srow = tid >> 1, hb = tid & 1;          // staging: row + 16-elem half
    int w    = tid >> 6, lane = tid & 63;
    int wr   = w >> 1,  wc = w & 1;             // wave -> 64x64 quadrant
    int r16  = lane & 15, kg = lane >> 4;

    f32x4 acc[4][4];
#pragma unroll
    for (int mi = 0; mi < 4; ++mi)
#pragma unroll
        for (int ni = 0; ni < 4; ++ni)
            acc[mi][ni] = (f32x4){0.f, 0.f, 0.f, 0.f};

    auto stage = [&](int kt, int buf) {
        int k0 = kt * 32;
        int seg = k0 >> 8;
        int kl  = (k0 & 255) + hb * 16;
        ushort* Ad = &As[buf][srow * 40 + hb * 16];
        if (seg < 2) {
            const ushort* src = (seg ? Aout : Ain) + (size_t)(row0 + srow) * 256 + kl;
            *(us8*)Ad       = *(const us8*)src;
            *(us8*)(Ad + 8) = *(const us8*)(src + 8);
        } else {
            int gr = row0 + srow;
            us8 pa, pb;
            if (gr < N_ENT) {
                const float* src = x + (size_t)gr * 256 + kl;
                const float* ls  = lrel + kl;
#pragma unroll
                for (int j = 0; j < 8; ++j) {
                    pa[j] = (short)f2b(src[j] * ls[j]);
                    pb[j] = (short)f2b(src[8 + j] * ls[8 + j]);
                }
            } else {
#pragma unroll
                for (int j = 0; j < 8; ++j) { pa[j] = 0; pb[j] = 0; }
            }
            *(us8*)Ad       = pa;
            *(us8*)(Ad + 8) = pb;
        }
        ushort* Bd = &Bs[buf][srow * 40 + hb * 16];
        const ushort* bsrc = wT + (size_t)(col0 + srow) * 768 + k0 + hb * 16;
        *(us8*)Bd       = *(const us8*)bsrc;
        *(us8*)(Bd + 8) = *(const us8*)(bsrc + 8);
    };

    stage(0, 0);
    __syncthreads();
    for (int kt = 0; kt < 24; ++kt) {
        int cur = kt & 1;
        if (kt + 1 < 24) stage(kt + 1, cur ^ 1);
        const ushort* Ab = &As[cur][(wr * 64 + r16) * 40 + kg * 8];
        const ushort* Bb = &Bs[cur][(wc * 64 + r16) * 40 + kg * 8];
        bf16x8 af[4], bfr[4];
#pragma unroll
        for (int i = 0; i < 4; ++i) {
            af[i]  = *(const bf16x8*)(Ab + i * 640);   // 16 rows * 40
            bfr[i] = *(const bf16x8*)(Bb + i * 640);
        }
#pragma unroll
        for (int mi = 0; mi < 4; ++mi)
#pragma unroll
            for (int ni = 0; ni < 4; ++ni)
                acc[mi][ni] = __builtin_amdgcn_mfma_f32_16x16x32_bf16(af[mi], bfr[ni], acc[mi][ni], 0, 0, 0);
        __syncthreads();
    }

#pragma unroll
    for (int mi = 0; mi < 4; ++mi) {
        int r = row0 + wr * 64 + mi * 16 + kg * 4;
#pragma unroll
        for (int ni = 0; ni < 4; ++ni) {
            int c = col0 + wc * 64 + ni * 16 + r16;
#pragma unroll
            for (int j = 0; j < 4; ++j) {
                int rr = r + j;
                if (rr < N_ENT) C[(size_t)rr * 256 + c] = acc[mi][ni][j];
            }
        }
    }
}

// ============ fallback: atomic aggregation + f32 GEMM ============
__global__ void degree_kernel(const int* __restrict__ ei, float* __restrict__ deg_in,
                              float* __restrict__ deg_out) {
    int e = blockIdx.x * blockDim.x + threadIdx.x;
    if (e >= NE2) return;
    int row = ei[e];
    if (e < EHALF) atomicAdd(&deg_in[row], 1.0f);
    else           atomicAdd(&deg_out[row], 1.0f);
}

__global__ void deginv_kernel(float* __restrict__ deg) {
    int i = blockIdx.x * blockDim.x + threadIdx.x;
    if (i >= 2 * N_ENT) return;
    float d = deg[i];
    deg[i] = d > 0.0f ? rsqrtf(d) : 0.0f;
}

__global__ __launch_bounds__(256) void aggregate_kernel(
        const int* __restrict__ ei, const int* __restrict__ et,
        const float* __restrict__ x, const float* __restrict__ rel,
        const float* __restrict__ dinv, float* __restrict__ agg, int base) {
    int wid  = (blockIdx.x * blockDim.x + threadIdx.x) >> 6;
    int lane = threadIdx.x & 63;
    if (wid >= EHALF) return;
    int e   = base + wid;
    int row = ei[e];
    int col = ei[NE2 + e];
    int t   = et[e];
    float s = dinv[row] * dinv[col];
    float4 xv = *(const float4*)(x   + (size_t)col * D + lane * 4);
    float4 rv = *(const float4*)(rel + (size_t)t   * D + lane * 4);
    float* dst = agg + (size_t)row * D + lane * 4;
    atomicAdd(dst + 0, xv.x * rv.x * s);
    atomicAdd(dst + 1, xv.y * rv.y * s);
    atomicAdd(dst + 2, xv.z * rv.z * s);
    atomicAdd(dst + 3, xv.w * rv.w * s);
}

template<bool ACC, bool COLSCALE>
__global__ __launch_bounds__(256) void gemm_kernel(
        const float* __restrict__ A, const float* __restrict__ W,
        const float* __restrict__ colscale, float* __restrict__ C, int M) {
    __shared__ float Asm[16][68];
    __shared__ float Bsm[16][64];
    int tid  = threadIdx.x;
    int row0 = blockIdx.x * 64;
    int col0 = blockIdx.y * 64;
    int tx = tid & 15, ty = tid >> 4;
    float acc[4][4] = {};
    int lr  = tid >> 2;
    int lc4 = (tid & 3) * 4;
    int wrw  = tid >> 4;
    int wc4 = (tid & 15) * 4;
    for (int k0 = 0; k0 < 256; k0 += 16) {
        float4 av = make_float4(0.f, 0.f, 0.f, 0.f);
        int ar = row0 + lr;
        if (ar < M) av = *(const float4*)(A + (size_t)ar * 256 + k0 + lc4);
        if (COLSCALE) {
            float4 cs = *(const float4*)(colscale + k0 + lc4);
            av.x *= cs.x; av.y *= cs.y; av.z *= cs.z; av.w *= cs.w;
        }
        Asm[lc4 + 0][lr] = av.x;
        Asm[lc4 + 1][lr] = av.y;
        Asm[lc4 + 2][lr] = av.z;
        Asm[lc4 + 3][lr] = av.w;
        *(float4*)&Bsm[wrw][wc4] = *(const float4*)(W + (size_t)(k0 + wrw) * 256 + col0 + wc4);
        __syncthreads();
#pragma unroll
        for (int k = 0; k < 16; ++k) {
            float4 a4 = *(const float4*)&Asm[k][ty * 4];
            float4 b4 = *(const float4*)&Bsm[k][tx * 4];
            float a[4] = {a4.x, a4.y, a4.z, a4.w};
            float b[4] = {b4.x, b4.y, b4.z, b4.w};
#pragma unroll
            for (int i = 0; i < 4; ++i)
#pragma unroll
                for (int j = 0; j < 4; ++j)
                    acc[i][j] = fmaf(a[i], b[j], acc[i][j]);
        }
        __syncthreads();
    }
#pragma unroll
    for (int i = 0; i < 4; ++i) {
        int r = row0 + ty * 4 + i;
        if (r >= M) continue;
#pragma unroll
        for (int j = 0; j < 4; ++j) {
            size_t o = (size_t)r * 256 + col0 + tx * 4 + j;
            C[o] = ACC ? C[o] + acc[i][j] : acc[i][j];
        }
    }
}

// ---------------- BatchNorm ----------------
__global__ __launch_bounds__(256) void bn_stats_kernel(
        const float* __restrict__ out, const float* __restrict__ bias,
        float* __restrict__ colsum, float* __restrict__ colsumsq) {
    int c  = threadIdx.x;
    int r0 = blockIdx.x * 64;
    float b = bias[c];
    float s = 0.f, sq = 0.f;
    int rend = min(r0 + 64, N_ENT);
    for (int r = r0; r < rend; ++r) {
        float v = out[(size_t)r * 256 + c] * (1.f / 3.f) + b;
        s += v; sq += v * v;
    }
    atomicAdd(&colsum[c], s);
    atomicAdd(&colsumsq[c], sq);
}

__global__ void bn_finalize_kernel(const float* __restrict__ colsum, const float* __restrict__ colsumsq,
                                   const float* __restrict__ bias, const float* __restrict__ gamma,
                                   const float* __restrict__ beta,
                                   float* __restrict__ colA, float* __restrict__ colB) {
    int c = threadIdx.x;
    float mean = colsum[c] * (1.f / N_ENT);
    float var  = colsumsq[c] * (1.f / N_ENT) - mean * mean;
    float sc   = rsqrtf(var + BN_EPS) * gamma[c];
    colA[c] = sc * (1.f / 3.f);
    colB[c] = (bias[c] - mean) * sc + beta[c];
}

__global__ __launch_bounds__(256) void bn_apply_kernel(
        float* __restrict__ out, const float* __restrict__ colA, const float* __restrict__ colB) {
    size_t i4 = (size_t)blockIdx.x * 256 + threadIdx.x;
    float4 v = ((const float4*)out)[i4];
    int c4 = (int)(i4 & 63) * 4;
    v.x = v.x * colA[c4 + 0] + colB[c4 + 0];
    v.y = v.y * colA[c4 + 1] + colB[c4 + 1];
    v.z = v.z * colA[c4 + 2] + colB[c4 + 2];
    v.w = v.w * colA[c4 + 3] + colB[c4 + 3];
    ((float4*)out)[i4] = v;
}

__global__ __launch_bounds__(256) void relgemm_kernel(
        const float* __restrict__ rel, const float* __restrict__ w, float* __restrict__ out) {
    int r = blockIdx.x;
    int c = threadIdx.x;
    float acc = 0.f;
    for (int k = 0; k < 256; ++k)
        acc = fmaf(rel[r * 256 + k], w[k * 256 + c], acc);
    out[r * 256 + c] = acc;
}

extern "C" void kernel_launch(void* const* d_in, const int* in_sizes, int n_in,
                              void* d_out, int out_size, void* d_ws, size_t ws_size,
                              hipStream_t stream) {
    const float* x        = (const float*)d_in[0];
    const int*   ei       = (const int*)d_in[1];
    const int*   et       = (const int*)d_in[2];
    const float* rel      = (const float*)d_in[3];
    const float* w_loop   = (const float*)d_in[4];
    const float* w_in     = (const float*)d_in[5];
    const float* w_out    = (const float*)d_in[6];
    const float* w_rel    = (const float*)d_in[7];
    const float* loop_rel = (const float*)d_in[8];
    const float* bias     = (const float*)d_in[9];
    const float* gamma    = (const float*)d_in[10];
    const float* beta     = (const float*)d_in[11];

    float* out     = (float*)d_out;
    float* rel_out = out + (size_t)N_ENT * D;
    const int* colidx = ei + NE2;

    // ---- workspace layout (MFMA/CSR path) ----
    char* ws = (char*)d_ws;
    size_t off = 0;
    ushort* agg_in16  = (ushort*)(ws + off); off += (size_t)MPAD * D * 2;  // 51.25 MB
    ushort* agg_out16 = (ushort*)(ws + off); off += (size_t)MPAD * D * 2;  // 51.25 MB
    int* rp_in   = (int*)(ws + off); off += 400016;
    int* rp_out  = (int*)(ws + off); off += 400016;
    float* dv_in  = (float*)(ws + off); off += 400016;
    float* dv_out = (float*)(ws + off); off += 400016;
    int* el_in  = (int*)(ws + off); off += (size_t)EHALF * 4;
    int* el_out = (int*)(ws + off); off += (size_t)EHALF * 4;
    ushort* wT  = (ushort*)(ws + off); off += 768 * 256 * 2;
    float* stats = (float*)(ws + off); off += 8192;
    size_t needed = off;
    float* colsum = stats, *colsumsq = stats + 256;
    float* colA = stats + 512, *colB = stats + 768;
    int* bsum = (int*)(stats + 1024);
    // cnt arrays aliased over agg_in16 (dead before agg_in16 is written)
    int* cnt_in  = (int*)agg_in16;
    int* cnt_out = cnt_in + 100004;

    if (ws_size >= needed) {
        hipMemsetAsync(cnt_in, 0, 2 * 100004 * 4, stream);
        hipMemsetAsync(stats, 0, 8192, stream);
        hist_kernel<<<(NE2 + 255) / 256, 256, 0, stream>>>(ei, cnt_in, cnt_out);
        scan1_kernel<<<dim3(98, 2), 256, 0, stream>>>(cnt_in, cnt_out, rp_in, rp_out, dv_in, dv_out, bsum);
        scan2_kernel<<<1, 64, 0, stream>>>(bsum);
        scan3_kernel<<<dim3(98, 2), 256, 0, stream>>>(rp_in, rp_out, cnt_in, cnt_out, bsum);
        scatter_kernel<<<(NE2 + 255) / 256, 256, 0, stream>>>(ei, cnt_in, cnt_out, el_in, el_out);
        wconv_kernel<<<256, 256, 0, stream>>>(w_in, w_out, w_loop, wT);

        agg_csr16_kernel<<<(N_ENT * 64 + 255) / 256, 256, 0, stream>>>(
            rp_in, el_in, colidx, et, dv_in, x, rel, agg_in16);
        agg_csr16_kernel<<<(N_ENT * 64 + 255) / 256, 256, 0, stream>>>(
            rp_out, el_out, colidx, et, dv_out, x, rel, agg_out16);

        fused_gemm_kernel<<<dim3(MPAD / 128, 2), 256, 0, stream>>>(
            agg_in16, agg_out16, x, loop_rel, wT, out);
    } else {
        // fallback: atomic aggregation + f32 GEMMs (fits 103.2 MB)
        float* agg = (float*)ws;
        float* deg = (float*)(ws + (size_t)N_ENT * D * 4);
        float* deg_in = deg, *deg_out = deg + N_ENT;
        float* fstats = deg + 2 * N_ENT;
        colsum = fstats; colsumsq = fstats + 256; colA = fstats + 512; colB = fstats + 768;
        hipMemsetAsync(deg, 0, (size_t)(2 * N_ENT + 1024) * 4, stream);
        degree_kernel<<<(NE2 + 255) / 256, 256, 0, stream>>>(ei, deg_in, deg_out);
        deginv_kernel<<<(2 * N_ENT + 255) / 256, 256, 0, stream>>>(deg);
        dim3 ggrid((N_ENT + 63) / 64, 4);
        hipMemsetAsync(agg, 0, (size_t)N_ENT * D * 4, stream);
        aggregate_kernel<<<EHALF / 4, 256, 0, stream>>>(ei, et, x, rel, deg_in, agg, 0);
        gemm_kernel<false, false><<<ggrid, 256, 0, stream>>>(agg, w_in, nullptr, out, N_ENT);
        hipMemsetAsync(agg, 0, (size_t)N_ENT * D * 4, stream);
        aggregate_kernel<<<EHALF / 4, 256, 0, stream>>>(ei, et, x, rel, deg_out, agg, EHALF);
        gemm_kernel<true, false><<<ggrid, 256, 0, stream>>>(agg, w_out, nullptr, out, N_ENT);
        gemm_kernel<true, true><<<ggrid, 256, 0, stream>>>(x, w_loop, loop_rel, out, N_ENT);
    }

    // batchnorm
    bn_stats_kernel<<<(N_ENT + 63) / 64, 256, 0, stream>>>(out, bias, colsum, colsumsq);
    bn_finalize_kernel<<<1, 256, 0, stream>>>(colsum, colsumsq, bias, gamma, beta, colA, colB);
    bn_apply_kernel<<<(N_ENT * 64) / 256, 256, 0, stream>>>(out, colA, colB);

    // relation output
    relgemm_kernel<<<NREL, 256, 0, stream>>>(rel, w_rel, rel_out);
}

// Round 4
// 497.968 us; speedup vs baseline: 8.1599x; 1.1078x over previous
//
#include <hip/hip_runtime.h>

#define N_ENT  100000
#define MPAD   100096           // 782 * 128
#define EHALF  500000
#define NE2    1000000
#define D      256
#define NREL   200
#define BN_EPS 1e-5f

typedef __attribute__((ext_vector_type(8))) short  bf16x8;
typedef __attribute__((ext_vector_type(8))) ushort us8;
typedef __attribute__((ext_vector_type(4))) float  f32x4;

__device__ __forceinline__ ushort f2b(float f) {
    unsigned u = __float_as_uint(f);
    return (ushort)((u + 0x7fffu + ((u >> 16) & 1u)) >> 16);
}
__device__ __forceinline__ float b2f(ushort u) {
    return __uint_as_float((unsigned)u << 16);
}

// ================= CSR build =================
__global__ __launch_bounds__(256) void hist_kernel(const int* __restrict__ ei,
                                                   int* __restrict__ cnt_in,
                                                   int* __restrict__ cnt_out) {
    int e = blockIdx.x * blockDim.x + threadIdx.x;
    if (e >= NE2) return;
    int row = ei[e];
    if (e < EHALF) atomicAdd(&cnt_in[row], 1);
    else           atomicAdd(&cnt_out[row], 1);
}

__global__ __launch_bounds__(256) void scan1_kernel(const int* __restrict__ cnt_in,
                                                    const int* __restrict__ cnt_out,
                                                    int* __restrict__ rp_in, int* __restrict__ rp_out,
                                                    float* __restrict__ dv_in, float* __restrict__ dv_out,
                                                    int* __restrict__ bsum) {
    int half = blockIdx.y;
    const int* cnt = half ? cnt_out : cnt_in;
    int* rp  = half ? rp_out : rp_in;
    float* dv = half ? dv_out : dv_in;
    __shared__ int sm[256];
    int tid = threadIdx.x;
    int base = blockIdx.x * 1024 + tid * 4;
    int v[4];
#pragma unroll
    for (int j = 0; j < 4; ++j) { int i = base + j; v[j] = (i < N_ENT) ? cnt[i] : 0; }
    int tsum = v[0] + v[1] + v[2] + v[3];
    sm[tid] = tsum;
    __syncthreads();
    for (int off = 1; off < 256; off <<= 1) {
        int t = (tid >= off) ? sm[tid - off] : 0;
        __syncthreads();
        sm[tid] += t;
        __syncthreads();
    }
    int run = sm[tid] - tsum;
#pragma unroll
    for (int j = 0; j < 4; ++j) {
        int i = base + j;
        if (i < N_ENT) {
            rp[i] = run;
            dv[i] = v[j] > 0 ? rsqrtf((float)v[j]) : 0.0f;
        }
        run += v[j];
    }
    if (tid == 255) bsum[half * 98 + blockIdx.x] = sm[255];
}

__global__ void scan2_kernel(int* __restrict__ bsum) {
    int h = threadIdx.x;
    if (h >= 2) return;
    int run = 0;
    for (int b = 0; b < 98; ++b) { int t = bsum[h * 98 + b]; bsum[h * 98 + b] = run; run += t; }
}

__global__ __launch_bounds__(256) void scan3_kernel(int* __restrict__ rp_in, int* __restrict__ rp_out,
                                                    int* __restrict__ cnt_in, int* __restrict__ cnt_out,
                                                    const int* __restrict__ bsum) {
    int half = blockIdx.y;
    int* rp  = half ? rp_out : rp_in;
    int* cnt = half ? cnt_out : cnt_in;
    int add = bsum[half * 98 + blockIdx.x];
    int base = blockIdx.x * 1024 + threadIdx.x * 4;
#pragma unroll
    for (int j = 0; j < 4; ++j) {
        int i = base + j;
        if (i < N_ENT) { int t = rp[i] + add; rp[i] = t; cnt[i] = t; }
    }
    if (blockIdx.x == 0 && threadIdx.x == 0) rp[N_ENT] = EHALF;
}

__global__ __launch_bounds__(256) void scatter_kernel(const int* __restrict__ ei,
                                                      int* __restrict__ cur_in, int* __restrict__ cur_out,
                                                      int* __restrict__ el_in, int* __restrict__ el_out) {
    int e = blockIdx.x * blockDim.x + threadIdx.x;
    if (e >= NE2) return;
    int row = ei[e];
    if (e < EHALF) { int p = atomicAdd(&cur_in[row], 1);  el_in[p]  = e; }
    else           { int p = atomicAdd(&cur_out[row], 1); el_out[p] = e; }
}

// ================= f32 -> bf16 bulk convert =================
__global__ __launch_bounds__(256) void conv16_kernel(const float* __restrict__ src,
                                                     ushort* __restrict__ dst, int n4) {
    int i = blockIdx.x * 256 + threadIdx.x;
    if (i >= n4) return;
    float4 v = ((const float4*)src)[i];
    ushort4 o;
    o.x = f2b(v.x); o.y = f2b(v.y); o.z = f2b(v.z); o.w = f2b(v.w);
    ((ushort4*)dst)[i] = o;
}

// ============ bf16 gather aggregation, both halves (grid.y) ============
__global__ __launch_bounds__(256) void agg16_kernel(
        const int* __restrict__ rp_in, const int* __restrict__ el_in,
        const float* __restrict__ dv_in, ushort* __restrict__ agg_in,
        const int* __restrict__ rp_out, const int* __restrict__ el_out,
        const float* __restrict__ dv_out, ushort* __restrict__ agg_out,
        const int* __restrict__ colidx, const int* __restrict__ et,
        const ushort* __restrict__ x16, const ushort* __restrict__ rel16) {
    int half = blockIdx.y;
    const int* rp     = half ? rp_out : rp_in;
    const int* elist  = half ? el_out : el_in;
    const float* dinv = half ? dv_out : dv_in;
    ushort* agg       = half ? agg_out : agg_in;
    int wid  = (blockIdx.x * blockDim.x + threadIdx.x) >> 6;
    int lane = threadIdx.x & 63;
    if (wid >= N_ENT) return;
    int s = rp[wid], eend = rp[wid + 1];
    float dr = dinv[wid];
    float4 acc = make_float4(0.f, 0.f, 0.f, 0.f);
    int e = (s < eend) ? elist[s] : 0;
    for (int p = s; p < eend; ++p) {
        int c = colidx[e];
        int t = et[e];
        int enext = (p + 1 < eend) ? elist[p + 1] : 0;
        float sc = dr * dinv[c];
        ushort4 xv = *(const ushort4*)(x16   + (size_t)c * D + lane * 4);
        ushort4 rv = *(const ushort4*)(rel16 + (size_t)t * D + lane * 4);
        acc.x = fmaf(b2f(xv.x) * b2f(rv.x), sc, acc.x);
        acc.y = fmaf(b2f(xv.y) * b2f(rv.y), sc, acc.y);
        acc.z = fmaf(b2f(xv.z) * b2f(rv.z), sc, acc.z);
        acc.w = fmaf(b2f(xv.w) * b2f(rv.w), sc, acc.w);
        e = enext;
    }
    ushort4 o;
    o.x = f2b(acc.x); o.y = f2b(acc.y); o.z = f2b(acc.z); o.w = f2b(acc.w);
    *(ushort4*)(agg + (size_t)wid * D + lane * 4) = o;
}

// ============ legacy f32-x aggregation (mid fallback) ============
__global__ __launch_bounds__(256) void agg_csr16_kernel(
        const int* __restrict__ rp, const int* __restrict__ elist,
        const int* __restrict__ colidx, const int* __restrict__ et,
        const float* __restrict__ dinv, const float* __restrict__ x,
        const float* __restrict__ rel, ushort* __restrict__ agg) {
    int wid  = (blockIdx.x * blockDim.x + threadIdx.x) >> 6;
    int lane = threadIdx.x & 63;
    if (wid >= N_ENT) return;
    int s = rp[wid], eend = rp[wid + 1];
    float dr = dinv[wid];
    float4 acc = make_float4(0.f, 0.f, 0.f, 0.f);
    int e = (s < eend) ? elist[s] : 0;
    for (int p = s; p < eend; ++p) {
        int c = colidx[e];
        int t = et[e];
        int enext = (p + 1 < eend) ? elist[p + 1] : 0;
        float sc = dr * dinv[c];
        float4 xv = *(const float4*)(x   + (size_t)c * D + lane * 4);
        float4 rv = *(const float4*)(rel + (size_t)t * D + lane * 4);
        acc.x = fmaf(xv.x * rv.x, sc, acc.x);
        acc.y = fmaf(xv.y * rv.y, sc, acc.y);
        acc.z = fmaf(xv.z * rv.z, sc, acc.z);
        acc.w = fmaf(xv.w * rv.w, sc, acc.w);
        e = enext;
    }
    ushort4 o;
    o.x = f2b(acc.x); o.y = f2b(acc.y); o.z = f2b(acc.z); o.w = f2b(acc.w);
    *(ushort4*)(agg + (size_t)wid * D + lane * 4) = o;
}

// ============ weight transpose -> bf16: wT[n][k], k in [0,768) ============
template<bool FOLD>
__global__ __launch_bounds__(256) void wconv_kernel(const float* __restrict__ w_in,
                                                    const float* __restrict__ w_out,
                                                    const float* __restrict__ w_loop,
                                                    const float* __restrict__ lrel,
                                                    ushort* __restrict__ wT) {
    int n = blockIdx.x;
    int k = threadIdx.x;
    wT[(size_t)n * 768 + 0   + k] = f2b(w_in [k * 256 + n]);
    wT[(size_t)n * 768 + 256 + k] = f2b(w_out[k * 256 + n]);
    float wl = w_loop[k * 256 + n];
    if (FOLD) wl *= lrel[k];
    wT[(size_t)n * 768 + 512 + k] = f2b(wl);
}

// ============ fused bf16 MFMA GEMM: C = [Ain|Aout|Xseg] @ wT^T (+BN partials) ====
// tile 128x128, BK=32, 4 waves (each 64x64), double-buffered LDS, row pad +8
template<bool X16M>
__global__ __launch_bounds__(256) void fused_gemm_kernel(
        const ushort* __restrict__ Ain, const ushort* __restrict__ Aout,
        const ushort* __restrict__ X16p,
        const float* __restrict__ xf, const float* __restrict__ lrel,
        const ushort* __restrict__ wT, float* __restrict__ C,
        float* __restrict__ colsum, float* __restrict__ colsumsq) {
    __shared__ ushort As[2][128 * 40];
    __shared__ ushort Bs[2][128 * 40];
    int tid  = threadIdx.x;
    int row0 = blockIdx.x * 128;
    int col0 = blockIdx.y * 128;
    int srow = tid >> 1, hb = tid & 1;
    int w    = tid >> 6, lane = tid & 63;
    int wr   = w >> 1,  wc = w & 1;
    int r16  = lane & 15, kg = lane >> 4;

    f32x4 acc[4][4];
#pragma unroll
    for (int mi = 0; mi < 4; ++mi)
#pragma unroll
        for (int ni = 0; ni < 4; ++ni)
            acc[mi][ni] = (f32x4){0.f, 0.f, 0.f, 0.f};

    auto stage = [&](int kt, int buf) {
        int k0 = kt * 32;
        int seg = k0 >> 8;
        int kl  = (k0 & 255) + hb * 16;
        ushort* Ad = &As[buf][srow * 40 + hb * 16];
        if (X16M || seg < 2) {
            const ushort* base = (seg == 0) ? Ain : (seg == 1) ? Aout : X16p;
            const ushort* src = base + (size_t)(row0 + srow) * 256 + kl;
            *(us8*)Ad       = *(const us8*)src;
            *(us8*)(Ad + 8) = *(const us8*)(src + 8);
        } else {
            int gr = row0 + srow;
            us8 pa, pb;
            if (gr < N_ENT) {
                const float* src = xf + (size_t)gr * 256 + kl;
                const float* ls  = lrel + kl;
#pragma unroll
                for (int j = 0; j < 8; ++j) {
                    pa[j] = (short)f2b(src[j] * ls[j]);
                    pb[j] = (short)f2b(src[8 + j] * ls[8 + j]);
                }
            } else {
#pragma unroll
                for (int j = 0; j < 8; ++j) { pa[j] = 0; pb[j] = 0; }
            }
            *(us8*)Ad       = pa;
            *(us8*)(Ad + 8) = pb;
        }
        ushort* Bd = &Bs[buf][srow * 40 + hb * 16];
        const ushort* bsrc = wT + (size_t)(col0 + srow) * 768 + k0 + hb * 16;
        *(us8*)Bd       = *(const us8*)bsrc;
        *(us8*)(Bd + 8) = *(const us8*)(bsrc + 8);
    };

    stage(0, 0);
    __syncthreads();
    for (int kt = 0; kt < 24; ++kt) {
        int cur = kt & 1;
        if (kt + 1 < 24) stage(kt + 1, cur ^ 1);
        const ushort* Ab = &As[cur][(wr * 64 + r16) * 40 + kg * 8];
        const ushort* Bb = &Bs[cur][(wc * 64 + r16) * 40 + kg * 8];
        bf16x8 af[4], bfr[4];
#pragma unroll
        for (int i = 0; i < 4; ++i) {
            af[i]  = *(const bf16x8*)(Ab + i * 640);
            bfr[i] = *(const bf16x8*)(Bb + i * 640);
        }
#pragma unroll
        for (int mi = 0; mi < 4; ++mi)
#pragma unroll
            for (int ni = 0; ni < 4; ++ni)
                acc[mi][ni] = __builtin_amdgcn_mfma_f32_16x16x32_bf16(af[mi], bfr[ni], acc[mi][ni], 0, 0, 0);
        __syncthreads();
    }

#pragma unroll
    for (int mi = 0; mi < 4; ++mi) {
        int r = row0 + wr * 64 + mi * 16 + kg * 4;
#pragma unroll
        for (int ni = 0; ni < 4; ++ni) {
            int c = col0 + wc * 64 + ni * 16 + r16;
#pragma unroll
            for (int j = 0; j < 4; ++j) {
                int rr = r + j;
                if (rr < N_ENT) C[(size_t)rr * 256 + c] = acc[mi][ni][j];
            }
        }
    }

    if (X16M) {
        // BN raw partial sums: pad rows contribute exact zeros (A pads zeroed)
#pragma unroll
        for (int ni = 0; ni < 4; ++ni) {
            float s = 0.f, ss = 0.f;
#pragma unroll
            for (int mi = 0; mi < 4; ++mi)
#pragma unroll
                for (int j = 0; j < 4; ++j) {
                    float v = acc[mi][ni][j];
                    s += v; ss += v * v;
                }
            s += __shfl_xor(s, 16); ss += __shfl_xor(ss, 16);
            s += __shfl_xor(s, 32); ss += __shfl_xor(ss, 32);
            if (kg == 0) {
                int c = col0 + wc * 64 + ni * 16 + r16;
                atomicAdd(&colsum[c], s);
                atomicAdd(&colsumsq[c], ss);
            }
        }
    }
}

// ---------------- BatchNorm ----------------
__global__ __launch_bounds__(256) void bn_stats_kernel(
        const float* __restrict__ out, const float* __restrict__ bias,
        float* __restrict__ colsum, float* __restrict__ colsumsq) {
    int c  = threadIdx.x;
    int r0 = blockIdx.x * 64;
    float b = bias[c];
    float s = 0.f, sq = 0.f;
    int rend = min(r0 + 64, N_ENT);
    for (int r = r0; r < rend; ++r) {
        float v = out[(size_t)r * 256 + c] * (1.f / 3.f) + b;
        s += v; sq += v * v;
    }
    atomicAdd(&colsum[c], s);
    atomicAdd(&colsumsq[c], sq);
}

// RAW=true: colsum/colsumsq hold raw sums (pre /3, pre bias)
template<bool RAW>
__global__ void bn_finalize_kernel(const float* __restrict__ colsum, const float* __restrict__ colsumsq,
                                   const float* __restrict__ bias, const float* __restrict__ gamma,
                                   const float* __restrict__ beta,
                                   float* __restrict__ colA, float* __restrict__ colB) {
    int c = threadIdx.x;
    float invN = 1.f / N_ENT;
    float mean, var;
    if (RAW) {
        float Er  = colsum[c] * invN;
        float Er2 = colsumsq[c] * invN;
        float b = bias[c];
        mean = Er * (1.f / 3.f) + b;
        var  = Er2 * (1.f / 9.f) + 2.f * b * Er * (1.f / 3.f) + b * b - mean * mean;
    } else {
        mean = colsum[c] * invN;
        var  = colsumsq[c] * invN - mean * mean;
    }
    float sc = rsqrtf(var + BN_EPS) * gamma[c];
    colA[c] = sc * (1.f / 3.f);
    colB[c] = (bias[c] - mean) * sc + beta[c];
}

__global__ __launch_bounds__(256) void bn_apply_kernel(
        float* __restrict__ out, const float* __restrict__ colA, const float* __restrict__ colB) {
    size_t i4 = (size_t)blockIdx.x * 256 + threadIdx.x;
    float4 v = ((const float4*)out)[i4];
    int c4 = (int)(i4 & 63) * 4;
    v.x = v.x * colA[c4 + 0] + colB[c4 + 0];
    v.y = v.y * colA[c4 + 1] + colB[c4 + 1];
    v.z = v.z * colA[c4 + 2] + colB[c4 + 2];
    v.w = v.w * colA[c4 + 3] + colB[c4 + 3];
    ((float4*)out)[i4] = v;
}

__global__ __launch_bounds__(256) void relgemm_kernel(
        const float* __restrict__ rel, const float* __restrict__ w, float* __restrict__ out) {
    int r = blockIdx.x;
    int c = threadIdx.x;
    float acc = 0.f;
    for (int k = 0; k < 256; ++k)
        acc = fmaf(rel[r * 256 + k], w[k * 256 + c], acc);
    out[r * 256 + c] = acc;
}

extern "C" void kernel_launch(void* const* d_in, const int* in_sizes, int n_in,
                              void* d_out, int out_size, void* d_ws, size_t ws_size,
                              hipStream_t stream) {
    const float* x        = (const float*)d_in[0];
    const int*   ei       = (const int*)d_in[1];
    const int*   et       = (const int*)d_in[2];
    const float* rel      = (const float*)d_in[3];
    const float* w_loop   = (const float*)d_in[4];
    const float* w_in     = (const float*)d_in[5];
    const float* w_out    = (const float*)d_in[6];
    const float* w_rel    = (const float*)d_in[7];
    const float* loop_rel = (const float*)d_in[8];
    const float* bias     = (const float*)d_in[9];
    const float* gamma    = (const float*)d_in[10];
    const float* beta     = (const float*)d_in[11];

    float* out     = (float*)d_out;
    float* rel_out = out + (size_t)N_ENT * D;
    const int* colidx = ei + NE2;

    // ---- workspace layout ----
    char* ws = (char*)d_ws;
    size_t off = 0;
    ushort* agg_in16  = (ushort*)(ws + off); off += (size_t)MPAD * D * 2;
    ushort* agg_out16 = (ushort*)(ws + off); off += (size_t)MPAD * D * 2;
    int* rp_in   = (int*)(ws + off); off += 400416;
    int* rp_out  = (int*)(ws + off); off += 400416;
    float* dv_in  = (float*)(ws + off); off += 400416;
    float* dv_out = (float*)(ws + off); off += 400416;
    int* el_in  = (int*)(ws + off); off += (size_t)EHALF * 4;
    int* el_out = (int*)(ws + off); off += (size_t)EHALF * 4;
    ushort* wT  = (ushort*)(ws + off); off += 768 * 256 * 2;
    float* stats = (float*)(ws + off); off += 8192;
    size_t needed_mid = off;
    ushort* x16   = (ushort*)(ws + off); off += (size_t)MPAD * D * 2;
    ushort* rel16 = (ushort*)(ws + off); off += (size_t)NREL * D * 2;
    size_t needed_full = off;

    float* colsum = stats, *colsumsq = stats + 256;
    float* colA = stats + 512, *colB = stats + 768;
    int* bsum = (int*)(stats + 1024);
    int* cnt_in  = (int*)agg_in16;           // dead before agg written
    int* cnt_out = cnt_in + 100004;

    if (ws_size >= needed_full) {
        // ======== full path: bf16 gathers + fused BN stats ========
        hipMemsetAsync(cnt_in, 0, 2 * 100004 * 4, stream);
        hipMemsetAsync(stats, 0, 8192, stream);
        hipMemsetAsync(agg_in16  + (size_t)N_ENT * D, 0, (MPAD - N_ENT) * D * 2, stream);
        hipMemsetAsync(agg_out16 + (size_t)N_ENT * D, 0, (MPAD - N_ENT) * D * 2, stream);
        hipMemsetAsync(x16       + (size_t)N_ENT * D, 0, (MPAD - N_ENT) * D * 2, stream);

        hist_kernel<<<(NE2 + 255) / 256, 256, 0, stream>>>(ei, cnt_in, cnt_out);
        scan1_kernel<<<dim3(98, 2), 256, 0, stream>>>(cnt_in, cnt_out, rp_in, rp_out, dv_in, dv_out, bsum);
        scan2_kernel<<<1, 64, 0, stream>>>(bsum);
        scan3_kernel<<<dim3(98, 2), 256, 0, stream>>>(rp_in, rp_out, cnt_in, cnt_out, bsum);
        scatter_kernel<<<(NE2 + 255) / 256, 256, 0, stream>>>(ei, cnt_in, cnt_out, el_in, el_out);

        conv16_kernel<<<(N_ENT * 64 + 255) / 256, 256, 0, stream>>>(x, x16, N_ENT * 64);
        conv16_kernel<<<(NREL * 64 + 255) / 256, 256, 0, stream>>>(rel, rel16, NREL * 64);
        wconv_kernel<true><<<256, 256, 0, stream>>>(w_in, w_out, w_loop, loop_rel, wT);

        agg16_kernel<<<dim3((N_ENT * 64 + 255) / 256, 2), 256, 0, stream>>>(
            rp_in, el_in, dv_in, agg_in16, rp_out, el_out, dv_out, agg_out16,
            colidx, et, x16, rel16);

        fused_gemm_kernel<true><<<dim3(MPAD / 128, 2), 256, 0, stream>>>(
            agg_in16, agg_out16, x16, nullptr, nullptr, wT, out, colsum, colsumsq);

        bn_finalize_kernel<true><<<1, 256, 0, stream>>>(colsum, colsumsq, bias, gamma, beta, colA, colB);
    } else {
        // ======== mid fallback: round-3 path (f32 x gathers, separate bn_stats) ====
        hipMemsetAsync(cnt_in, 0, 2 * 100004 * 4, stream);
        hipMemsetAsync(stats, 0, 8192, stream);
        hist_kernel<<<(NE2 + 255) / 256, 256, 0, stream>>>(ei, cnt_in, cnt_out);
        scan1_kernel<<<dim3(98, 2), 256, 0, stream>>>(cnt_in, cnt_out, rp_in, rp_out, dv_in, dv_out, bsum);
        scan2_kernel<<<1, 64, 0, stream>>>(bsum);
        scan3_kernel<<<dim3(98, 2), 256, 0, stream>>>(rp_in, rp_out, cnt_in, cnt_out, bsum);
        scatter_kernel<<<(NE2 + 255) / 256, 256, 0, stream>>>(ei, cnt_in, cnt_out, el_in, el_out);
        wconv_kernel<false><<<256, 256, 0, stream>>>(w_in, w_out, w_loop, loop_rel, wT);

        agg_csr16_kernel<<<(N_ENT * 64 + 255) / 256, 256, 0, stream>>>(
            rp_in, el_in, colidx, et, dv_in, x, rel, agg_in16);
        agg_csr16_kernel<<<(N_ENT * 64 + 255) / 256, 256, 0, stream>>>(
            rp_out, el_out, colidx, et, dv_out, x, rel, agg_out16);

        fused_gemm_kernel<false><<<dim3(MPAD / 128, 2), 256, 0, stream>>>(
            agg_in16, agg_out16, nullptr, x, loop_rel, wT, out, colsum, colsumsq);

        bn_stats_kernel<<<(N_ENT + 63) / 64, 256, 0, stream>>>(out, bias, colsum, colsumsq);
        bn_finalize_kernel<false><<<1, 256, 0, stream>>>(colsum, colsumsq, bias, gamma, beta, colA, colB);
    }

    bn_apply_kernel<<<(N_ENT * 64) / 256, 256, 0, stream>>>(out, colA, colB);
    relgemm_kernel<<<NREL, 256, 0, stream>>>(rel, w_rel, rel_out);
}

// Round 6
// 440.436 us; speedup vs baseline: 9.2257x; 1.1306x over previous
//
#include <hip/hip_runtime.h>

#define N_ENT  100000
#define MPAD   100096           // 782 * 128
#define EHALF  500000
#define NE2    1000000
#define D      256
#define NREL   200
#define BN_EPS 1e-5f

typedef __attribute__((ext_vector_type(8))) short  bf16x8;
typedef __attribute__((ext_vector_type(8))) ushort us8;
typedef __attribute__((ext_vector_type(4))) float  f32x4;

__device__ __forceinline__ ushort f2b(float f) {
    unsigned u = __float_as_uint(f);
    return (ushort)((u + 0x7fffu + ((u >> 16) & 1u)) >> 16);
}
__device__ __forceinline__ float b2f(ushort u) {
    return __uint_as_float((unsigned)u << 16);
}

// ================= CSR build =================
__global__ __launch_bounds__(256) void hist_kernel(const int* __restrict__ ei,
                                                   int* __restrict__ cnt_in,
                                                   int* __restrict__ cnt_out) {
    int e = blockIdx.x * blockDim.x + threadIdx.x;
    if (e >= NE2) return;
    int row = ei[e];
    if (e < EHALF) atomicAdd(&cnt_in[row], 1);
    else           atomicAdd(&cnt_out[row], 1);
}

__global__ __launch_bounds__(256) void scan1_kernel(const int* __restrict__ cnt_in,
                                                    const int* __restrict__ cnt_out,
                                                    int* __restrict__ rp_in, int* __restrict__ rp_out,
                                                    float* __restrict__ dv_in, float* __restrict__ dv_out,
                                                    int* __restrict__ bsum) {
    int half = blockIdx.y;
    const int* cnt = half ? cnt_out : cnt_in;
    int* rp  = half ? rp_out : rp_in;
    float* dv = half ? dv_out : dv_in;
    __shared__ int sm[256];
    int tid = threadIdx.x;
    int base = blockIdx.x * 1024 + tid * 4;
    int v[4];
#pragma unroll
    for (int j = 0; j < 4; ++j) { int i = base + j; v[j] = (i < N_ENT) ? cnt[i] : 0; }
    int tsum = v[0] + v[1] + v[2] + v[3];
    sm[tid] = tsum;
    __syncthreads();
    for (int off = 1; off < 256; off <<= 1) {
        int t = (tid >= off) ? sm[tid - off] : 0;
        __syncthreads();
        sm[tid] += t;
        __syncthreads();
    }
    int run = sm[tid] - tsum;
#pragma unroll
    for (int j = 0; j < 4; ++j) {
        int i = base + j;
        if (i < N_ENT) {
            rp[i] = run;
            dv[i] = v[j] > 0 ? rsqrtf((float)v[j]) : 0.0f;
        }
        run += v[j];
    }
    if (tid == 255) bsum[half * 98 + blockIdx.x] = sm[255];
}

// scan of 98 block sums per half + zero BN stat accumulators
__global__ void scan2_kernel(int* __restrict__ bsum, float* __restrict__ stats) {
    int tid = threadIdx.x;
    stats[tid]       = 0.f;   // colsum
    stats[tid + 256] = 0.f;   // colsumsq
    if (tid < 2) {
        int run = 0;
        for (int b = 0; b < 98; ++b) { int t = bsum[tid * 98 + b]; bsum[tid * 98 + b] = run; run += t; }
    }
}

__global__ __launch_bounds__(256) void scan3_kernel(int* __restrict__ rp_in, int* __restrict__ rp_out,
                                                    int* __restrict__ cnt_in, int* __restrict__ cnt_out,
                                                    const int* __restrict__ bsum) {
    int half = blockIdx.y;
    int* rp  = half ? rp_out : rp_in;
    int* cnt = half ? cnt_out : cnt_in;
    int add = bsum[half * 98 + blockIdx.x];
    int base = blockIdx.x * 1024 + threadIdx.x * 4;
#pragma unroll
    for (int j = 0; j < 4; ++j) {
        int i = base + j;
        if (i < N_ENT) { int t = rp[i] + add; rp[i] = t; cnt[i] = t; }
    }
    if (blockIdx.x == 0 && threadIdx.x == 0) rp[N_ENT] = EHALF;
}

// packed scatter: el2[p] = {col, type, norm_scale_bits, 0}
__global__ __launch_bounds__(256) void scatterp_kernel(const int* __restrict__ ei,
                                                       const int* __restrict__ et,
                                                       const float* __restrict__ dv_in,
                                                       const float* __restrict__ dv_out,
                                                       int* __restrict__ cur_in, int* __restrict__ cur_out,
                                                       int4* __restrict__ el2_in, int4* __restrict__ el2_out) {
    int e = blockIdx.x * blockDim.x + threadIdx.x;
    if (e >= NE2) return;
    int row = ei[e];
    int col = ei[NE2 + e];
    int t   = et[e];
    if (e < EHALF) {
        float sc = dv_in[row] * dv_in[col];
        int p = atomicAdd(&cur_in[row], 1);
        el2_in[p] = make_int4(col, t, __float_as_int(sc), 0);
    } else {
        float sc = dv_out[row] * dv_out[col];
        int p = atomicAdd(&cur_out[row], 1);
        el2_out[p] = make_int4(col, t, __float_as_int(sc), 0);
    }
}

// legacy scatter (mid fallback)
__global__ __launch_bounds__(256) void scatter_kernel(const int* __restrict__ ei,
                                                      int* __restrict__ cur_in, int* __restrict__ cur_out,
                                                      int* __restrict__ el_in, int* __restrict__ el_out) {
    int e = blockIdx.x * blockDim.x + threadIdx.x;
    if (e >= NE2) return;
    int row = ei[e];
    if (e < EHALF) { int p = atomicAdd(&cur_in[row], 1);  el_in[p]  = e; }
    else           { int p = atomicAdd(&cur_out[row], 1); el_out[p] = e; }
}

// ============ prep: x/rel -> bf16, wT build, rel_out GEMM, pad zero ============
#define PB_CONVX  25000              // N_ENT*D/4/256
#define PB_CONVR  (PB_CONVX + 50)    // NREL*D/4/256
#define PB_WCONV  (PB_CONVR + 256)
#define PB_RELG   (PB_WCONV + 200)
#define PB_PADS   (PB_RELG + 72)     // 3 arrays * 24 blocks
__global__ __launch_bounds__(256) void prep_kernel(
        const float* __restrict__ x, const float* __restrict__ rel,
        const float* __restrict__ w_in, const float* __restrict__ w_out,
        const float* __restrict__ w_loop, const float* __restrict__ lrel,
        const float* __restrict__ w_rel,
        ushort* __restrict__ x16, ushort* __restrict__ rel16,
        ushort* __restrict__ wT, float* __restrict__ rel_out,
        ushort* __restrict__ agg_in, ushort* __restrict__ agg_out) {
    int b = blockIdx.x, tid = threadIdx.x;
    if (b < PB_CONVX) {
        int i = b * 256 + tid;
        float4 v = ((const float4*)x)[i];
        ushort4 o; o.x = f2b(v.x); o.y = f2b(v.y); o.z = f2b(v.z); o.w = f2b(v.w);
        ((ushort4*)x16)[i] = o;
    } else if (b < PB_CONVR) {
        int i = (b - PB_CONVX) * 256 + tid;
        float4 v = ((const float4*)rel)[i];
        ushort4 o; o.x = f2b(v.x); o.y = f2b(v.y); o.z = f2b(v.z); o.w = f2b(v.w);
        ((ushort4*)rel16)[i] = o;
    } else if (b < PB_WCONV) {
        int n = b - PB_CONVR;
        int k = tid;
        wT[(size_t)n * 768 + 0   + k] = f2b(w_in [k * 256 + n]);
        wT[(size_t)n * 768 + 256 + k] = f2b(w_out[k * 256 + n]);
        wT[(size_t)n * 768 + 512 + k] = f2b(w_loop[k * 256 + n] * lrel[k]);
    } else if (b < PB_RELG) {
        int r = b - PB_WCONV;
        int c = tid;
        float a = 0.f;
        for (int k = 0; k < 256; ++k)
            a = fmaf(rel[r * 256 + k], w_rel[k * 256 + c], a);
        rel_out[r * 256 + c] = a;
    } else {
        int idx = b - PB_RELG;            // [0,72)
        int arr = idx / 24, blk = idx % 24;
        ushort* base = (arr == 0) ? agg_in : (arr == 1) ? agg_out : x16;
        int i = blk * 256 + tid;          // [0,6144) ushort4s = (MPAD-N_ENT)*D
        ((ushort4*)(base + (size_t)N_ENT * D))[i] = (ushort4){0, 0, 0, 0};
    }
}

// ============ packed bf16 gather aggregation, 4-edge batched ============
__global__ __launch_bounds__(256) void agg16p_kernel(
        const int* __restrict__ rp_in, const int4* __restrict__ el2_in, ushort* __restrict__ agg_in,
        const int* __restrict__ rp_out, const int4* __restrict__ el2_out, ushort* __restrict__ agg_out,
        const ushort* __restrict__ x16, const ushort* __restrict__ rel16) {
    int half = blockIdx.y;
    const int*  rp  = half ? rp_out  : rp_in;
    const int4* el2 = half ? el2_out : el2_in;
    ushort* agg     = half ? agg_out : agg_in;
    int wid  = (blockIdx.x * blockDim.x + threadIdx.x) >> 6;
    int lane = threadIdx.x & 63;
    if (wid >= N_ENT) return;
    int s = rp[wid], eend = rp[wid + 1];
    float4 acc = make_float4(0.f, 0.f, 0.f, 0.f);
    for (int p = s; p < eend; p += 4) {
        int4  r[4];
        float sc[4];
#pragma unroll
        for (int i = 0; i < 4; ++i) {
            int q = (p + i < eend) ? p + i : eend - 1;
            r[i]  = el2[q];
            sc[i] = (p + i < eend) ? __int_as_float(r[i].z) : 0.f;
        }
        ushort4 xv[4], rv[4];
#pragma unroll
        for (int i = 0; i < 4; ++i) {
            xv[i] = *(const ushort4*)(x16   + (size_t)r[i].x * D + lane * 4);
            rv[i] = *(const ushort4*)(rel16 + (size_t)r[i].y * D + lane * 4);
        }
#pragma unroll
        for (int i = 0; i < 4; ++i) {
            acc.x = fmaf(b2f(xv[i].x) * b2f(rv[i].x), sc[i], acc.x);
            acc.y = fmaf(b2f(xv[i].y) * b2f(rv[i].y), sc[i], acc.y);
            acc.z = fmaf(b2f(xv[i].z) * b2f(rv[i].z), sc[i], acc.z);
            acc.w = fmaf(b2f(xv[i].w) * b2f(rv[i].w), sc[i], acc.w);
        }
    }
    ushort4 o;
    o.x = f2b(acc.x); o.y = f2b(acc.y); o.z = f2b(acc.z); o.w = f2b(acc.w);
    *(ushort4*)(agg + (size_t)wid * D + lane * 4) = o;
}

// ============ legacy f32-x aggregation (mid fallback) ============
__global__ __launch_bounds__(256) void agg_csr16_kernel(
        const int* __restrict__ rp, const int* __restrict__ elist,
        const int* __restrict__ colidx, const int* __restrict__ et,
        const float* __restrict__ dinv, const float* __restrict__ x,
        const float* __restrict__ rel, ushort* __restrict__ agg) {
    int wid  = (blockIdx.x * blockDim.x + threadIdx.x) >> 6;
    int lane = threadIdx.x & 63;
    if (wid >= N_ENT) return;
    int s = rp[wid], eend = rp[wid + 1];
    float dr = dinv[wid];
    float4 acc = make_float4(0.f, 0.f, 0.f, 0.f);
    int e = (s < eend) ? elist[s] : 0;
    for (int p = s; p < eend; ++p) {
        int c = colidx[e];
        int t = et[e];
        int enext = (p + 1 < eend) ? elist[p + 1] : 0;
        float sc = dr * dinv[c];
        float4 xv = *(const float4*)(x   + (size_t)c * D + lane * 4);
        float4 rv = *(const float4*)(rel + (size_t)t * D + lane * 4);
        acc.x = fmaf(xv.x * rv.x, sc, acc.x);
        acc.y = fmaf(xv.y * rv.y, sc, acc.y);
        acc.z = fmaf(xv.z * rv.z, sc, acc.z);
        acc.w = fmaf(xv.w * rv.w, sc, acc.w);
        e = enext;
    }
    ushort4 o;
    o.x = f2b(acc.x); o.y = f2b(acc.y); o.z = f2b(acc.z); o.w = f2b(acc.w);
    *(ushort4*)(agg + (size_t)wid * D + lane * 4) = o;
}

// mid-fallback weight transpose (no lrel fold)
__global__ __launch_bounds__(256) void wconv_kernel(const float* __restrict__ w_in,
                                                    const float* __restrict__ w_out,
                                                    const float* __restrict__ w_loop,
                                                    ushort* __restrict__ wT) {
    int n = blockIdx.x;
    int k = threadIdx.x;
    wT[(size_t)n * 768 + 0   + k] = f2b(w_in [k * 256 + n]);
    wT[(size_t)n * 768 + 256 + k] = f2b(w_out[k * 256 + n]);
    wT[(size_t)n * 768 + 512 + k] = f2b(w_loop[k * 256 + n]);
}

// ============ fused bf16 MFMA GEMM: C = [Ain|Aout|Xseg] @ wT^T (+BN partials) ====
template<bool X16M>
__global__ __launch_bounds__(256) void fused_gemm_kernel(
        const ushort* __restrict__ Ain, const ushort* __restrict__ Aout,
        const ushort* __restrict__ X16p,
        const float* __restrict__ xf, const float* __restrict__ lrel,
        const ushort* __restrict__ wT, float* __restrict__ C,
        float* __restrict__ colsum, float* __restrict__ colsumsq) {
    __shared__ ushort As[2][128 * 40];
    __shared__ ushort Bs[2][128 * 40];
    int tid  = threadIdx.x;
    int row0 = blockIdx.x * 128;
    int col0 = blockIdx.y * 128;
    int srow = tid >> 1, hb = tid & 1;
    int w    = tid >> 6, lane = tid & 63;
    int wr   = w >> 1,  wc = w & 1;
    int r16  = lane & 15, kg = lane >> 4;

    f32x4 acc[4][4];
#pragma unroll
    for (int mi = 0; mi < 4; ++mi)
#pragma unroll
        for (int ni = 0; ni < 4; ++ni)
            acc[mi][ni] = (f32x4){0.f, 0.f, 0.f, 0.f};

    auto stage = [&](int kt, int buf) {
        int k0 = kt * 32;
        int seg = k0 >> 8;
        int kl  = (k0 & 255) + hb * 16;
        ushort* Ad = &As[buf][srow * 40 + hb * 16];
        if (X16M || seg < 2) {
            const ushort* base = (seg == 0) ? Ain : (seg == 1) ? Aout : X16p;
            const ushort* src = base + (size_t)(row0 + srow) * 256 + kl;
            *(us8*)Ad       = *(const us8*)src;
            *(us8*)(Ad + 8) = *(const us8*)(src + 8);
        } else {
            int gr = row0 + srow;
            us8 pa, pb;
            if (gr < N_ENT) {
                const float* src = xf + (size_t)gr * 256 + kl;
                const float* ls  = lrel + kl;
#pragma unroll
                for (int j = 0; j < 8; ++j) {
                    pa[j] = (short)f2b(src[j] * ls[j]);
                    pb[j] = (short)f2b(src[8 + j] * ls[8 + j]);
                }
            } else {
#pragma unroll
                for (int j = 0; j < 8; ++j) { pa[j] = 0; pb[j] = 0; }
            }
            *(us8*)Ad       = pa;
            *(us8*)(Ad + 8) = pb;
        }
        ushort* Bd = &Bs[buf][srow * 40 + hb * 16];
        const ushort* bsrc = wT + (size_t)(col0 + srow) * 768 + k0 + hb * 16;
        *(us8*)Bd       = *(const us8*)bsrc;
        *(us8*)(Bd + 8) = *(const us8*)(bsrc + 8);
    };

    stage(0, 0);
    __syncthreads();
    for (int kt = 0; kt < 24; ++kt) {
        int cur = kt & 1;
        if (kt + 1 < 24) stage(kt + 1, cur ^ 1);
        const ushort* Ab = &As[cur][(wr * 64 + r16) * 40 + kg * 8];
        const ushort* Bb = &Bs[cur][(wc * 64 + r16) * 40 + kg * 8];
        bf16x8 af[4], bfr[4];
#pragma unroll
        for (int i = 0; i < 4; ++i) {
            af[i]  = *(const bf16x8*)(Ab + i * 640);
            bfr[i] = *(const bf16x8*)(Bb + i * 640);
        }
#pragma unroll
        for (int mi = 0; mi < 4; ++mi)
#pragma unroll
            for (int ni = 0; ni < 4; ++ni)
                acc[mi][ni] = __builtin_amdgcn_mfma_f32_16x16x32_bf16(af[mi], bfr[ni], acc[mi][ni], 0, 0, 0);
        __syncthreads();
    }

#pragma unroll
    for (int mi = 0; mi < 4; ++mi) {
        int r = row0 + wr * 64 + mi * 16 + kg * 4;
#pragma unroll
        for (int ni = 0; ni < 4; ++ni) {
            int c = col0 + wc * 64 + ni * 16 + r16;
#pragma unroll
            for (int j = 0; j < 4; ++j) {
                int rr = r + j;
                if (rr < N_ENT) C[(size_t)rr * 256 + c] = acc[mi][ni][j];
            }
        }
    }

    if (X16M) {
#pragma unroll
        for (int ni = 0; ni < 4; ++ni) {
            float s = 0.f, ss = 0.f;
#pragma unroll
            for (int mi = 0; mi < 4; ++mi)
#pragma unroll
                for (int j = 0; j < 4; ++j) {
                    float v = acc[mi][ni][j];
                    s += v; ss += v * v;
                }
            s += __shfl_xor(s, 16); ss += __shfl_xor(ss, 16);
            s += __shfl_xor(s, 32); ss += __shfl_xor(ss, 32);
            if (kg == 0) {
                int c = col0 + wc * 64 + ni * 16 + r16;
                atomicAdd(&colsum[c], s);
                atomicAdd(&colsumsq[c], ss);
            }
        }
    }
}

// ---------------- BatchNorm ----------------
__global__ __launch_bounds__(256) void bn_stats_kernel(
        const float* __restrict__ out, const float* __restrict__ bias,
        float* __restrict__ colsum, float* __restrict__ colsumsq) {
    int c  = threadIdx.x;
    int r0 = blockIdx.x * 64;
    float b = bias[c];
    float s = 0.f, sq = 0.f;
    int rend = min(r0 + 64, N_ENT);
    for (int r = r0; r < rend; ++r) {
        float v = out[(size_t)r * 256 + c] * (1.f / 3.f) + b;
        s += v; sq += v * v;
    }
    atomicAdd(&colsum[c], s);
    atomicAdd(&colsumsq[c], sq);
}

template<bool RAW>
__global__ void bn_finalize_kernel(const float* __restrict__ colsum, const float* __restrict__ colsumsq,
                                   const float* __restrict__ bias, const float* __restrict__ gamma,
                                   const float* __restrict__ beta,
                                   float* __restrict__ colA, float* __restrict__ colB) {
    int c = threadIdx.x;
    float invN = 1.f / N_ENT;
    float mean, var;
    if (RAW) {
        float Er  = colsum[c] * invN;
        float Er2 = colsumsq[c] * invN;
        float b = bias[c];
        mean = Er * (1.f / 3.f) + b;
        var  = Er2 * (1.f / 9.f) + 2.f * b * Er * (1.f / 3.f) + b * b - mean * mean;
    } else {
        mean = colsum[c] * invN;
        var  = colsumsq[c] * invN - mean * mean;
    }
    float sc = rsqrtf(var + BN_EPS) * gamma[c];
    colA[c] = sc * (1.f / 3.f);
    colB[c] = (bias[c] - mean) * sc + beta[c];
}

__global__ __launch_bounds__(256) void bn_apply_kernel(
        float* __restrict__ out, const float* __restrict__ colA, const float* __restrict__ colB) {
    size_t i4 = (size_t)blockIdx.x * 256 + threadIdx.x;
    float4 v = ((const float4*)out)[i4];
    int c4 = (int)(i4 & 63) * 4;
    v.x = v.x * colA[c4 + 0] + colB[c4 + 0];
    v.y = v.y * colA[c4 + 1] + colB[c4 + 1];
    v.z = v.z * colA[c4 + 2] + colB[c4 + 2];
    v.w = v.w * colA[c4 + 3] + colB[c4 + 3];
    ((float4*)out)[i4] = v;
}

__global__ __launch_bounds__(256) void relgemm_kernel(
        const float* __restrict__ rel, const float* __restrict__ w, float* __restrict__ out) {
    int r = blockIdx.x;
    int c = threadIdx.x;
    float acc = 0.f;
    for (int k = 0; k < 256; ++k)
        acc = fmaf(rel[r * 256 + k], w[k * 256 + c], acc);
    out[r * 256 + c] = acc;
}

extern "C" void kernel_launch(void* const* d_in, const int* in_sizes, int n_in,
                              void* d_out, int out_size, void* d_ws, size_t ws_size,
                              hipStream_t stream) {
    const float* x        = (const float*)d_in[0];
    const int*   ei       = (const int*)d_in[1];
    const int*   et       = (const int*)d_in[2];
    const float* rel      = (const float*)d_in[3];
    const float* w_loop   = (const float*)d_in[4];
    const float* w_in     = (const float*)d_in[5];
    const float* w_out    = (const float*)d_in[6];
    const float* w_rel    = (const float*)d_in[7];
    const float* loop_rel = (const float*)d_in[8];
    const float* bias     = (const float*)d_in[9];
    const float* gamma    = (const float*)d_in[10];
    const float* beta     = (const float*)d_in[11];

    float* out     = (float*)d_out;
    float* rel_out = out + (size_t)N_ENT * D;
    const int* colidx = ei + NE2;

    // ---- workspace layout (full path) ----
    char* ws = (char*)d_ws;
    size_t off = 0;
    ushort* agg_in16  = (ushort*)(ws + off); off += (size_t)MPAD * D * 2;
    ushort* agg_out16 = (ushort*)(ws + off); off += (size_t)MPAD * D * 2;
    int* rp_in   = (int*)(ws + off); off += 400416;
    int* rp_out  = (int*)(ws + off); off += 400416;
    float* dv_in  = (float*)(ws + off); off += 400416;
    float* dv_out = (float*)(ws + off); off += 400416;
    int4* el2_in  = (int4*)(ws + off); off += (size_t)EHALF * 16;
    int4* el2_out = (int4*)(ws + off); off += (size_t)EHALF * 16;
    ushort* wT  = (ushort*)(ws + off); off += 768 * 256 * 2;
    float* stats = (float*)(ws + off); off += 8192;
    ushort* x16   = (ushort*)(ws + off); off += (size_t)MPAD * D * 2;
    ushort* rel16 = (ushort*)(ws + off); off += (size_t)NREL * D * 2;
    size_t needed_full = off;

    float* colsum = stats, *colsumsq = stats + 256;
    float* colA = stats + 512, *colB = stats + 768;
    int* bsum = (int*)(stats + 1024);
    int* cnt_in  = (int*)agg_in16;            // dead before agg written
    int* cnt_out = cnt_in + 100004;

    if (ws_size >= needed_full) {
        // ======== full path: packed records + batched bf16 gathers ========
        hipMemsetAsync(cnt_in, 0, 2 * 100004 * 4, stream);

        hist_kernel<<<(NE2 + 255) / 256, 256, 0, stream>>>(ei, cnt_in, cnt_out);
        scan1_kernel<<<dim3(98, 2), 256, 0, stream>>>(cnt_in, cnt_out, rp_in, rp_out, dv_in, dv_out, bsum);
        scan2_kernel<<<1, 256, 0, stream>>>(bsum, stats);
        scan3_kernel<<<dim3(98, 2), 256, 0, stream>>>(rp_in, rp_out, cnt_in, cnt_out, bsum);
        scatterp_kernel<<<(NE2 + 255) / 256, 256, 0, stream>>>(ei, et, dv_in, dv_out,
                                                               cnt_in, cnt_out, el2_in, el2_out);
        prep_kernel<<<PB_PADS, 256, 0, stream>>>(x, rel, w_in, w_out, w_loop, loop_rel, w_rel,
                                                 x16, rel16, wT, rel_out, agg_in16, agg_out16);

        agg16p_kernel<<<dim3((N_ENT * 64 + 255) / 256, 2), 256, 0, stream>>>(
            rp_in, el2_in, agg_in16, rp_out, el2_out, agg_out16, x16, rel16);

        fused_gemm_kernel<true><<<dim3(MPAD / 128, 2), 256, 0, stream>>>(
            agg_in16, agg_out16, x16, nullptr, nullptr, wT, out, colsum, colsumsq);

        bn_finalize_kernel<true><<<1, 256, 0, stream>>>(colsum, colsumsq, bias, gamma, beta, colA, colB);
        bn_apply_kernel<<<(N_ENT * 64) / 256, 256, 0, stream>>>(out, colA, colB);
    } else {
        // ======== mid fallback: round-3 style (f32 gathers, separate bn_stats) ====
        int* el_in  = (int*)el2_in;
        int* el_out = el_in + EHALF;
        hipMemsetAsync(cnt_in, 0, 2 * 100004 * 4, stream);
        hist_kernel<<<(NE2 + 255) / 256, 256, 0, stream>>>(ei, cnt_in, cnt_out);
        scan1_kernel<<<dim3(98, 2), 256, 0, stream>>>(cnt_in, cnt_out, rp_in, rp_out, dv_in, dv_out, bsum);
        scan2_kernel<<<1, 256, 0, stream>>>(bsum, stats);
        scan3_kernel<<<dim3(98, 2), 256, 0, stream>>>(rp_in, rp_out, cnt_in, cnt_out, bsum);
        scatter_kernel<<<(NE2 + 255) / 256, 256, 0, stream>>>(ei, cnt_in, cnt_out, el_in, el_out);
        wconv_kernel<<<256, 256, 0, stream>>>(w_in, w_out, w_loop, wT);

        agg_csr16_kernel<<<(N_ENT * 64 + 255) / 256, 256, 0, stream>>>(
            rp_in, el_in, colidx, et, dv_in, x, rel, agg_in16);
        agg_csr16_kernel<<<(N_ENT * 64 + 255) / 256, 256, 0, stream>>>(
            rp_out, el_out, colidx, et, dv_out, x, rel, agg_out16);

        fused_gemm_kernel<false><<<dim3(MPAD / 128, 2), 256, 0, stream>>>(
            agg_in16, agg_out16, nullptr, x, loop_rel, wT, out, colsum, colsumsq);

        bn_stats_kernel<<<(N_ENT + 63) / 64, 256, 0, stream>>>(out, bias, colsum, colsumsq);
        bn_finalize_kernel<false><<<1, 256, 0, stream>>>(colsum, colsumsq, bias, gamma, beta, colA, colB);
        bn_apply_kernel<<<(N_ENT * 64) / 256, 256, 0, stream>>>(out, colA, colB);
        relgemm_kernel<<<NREL, 256, 0, stream>>>(rel, w_rel, rel_out);
    }
}

// Round 7
// 420.025 us; speedup vs baseline: 9.6741x; 1.0486x over previous
//
#include <hip/hip_runtime.h>

#define N_ENT  100000
#define MPAD   100096           // 782 * 128
#define EHALF  500000
#define NE2    1000000
#define D      256
#define NREL   200
#define BN_EPS 1e-5f

typedef __attribute__((ext_vector_type(8))) short  bf16x8;
typedef __attribute__((ext_vector_type(8))) ushort us8;
typedef __attribute__((ext_vector_type(4))) float  f32x4;

__device__ __forceinline__ ushort f2b(float f) {
    unsigned u = __float_as_uint(f);
    return (ushort)((u + 0x7fffu + ((u >> 16) & 1u)) >> 16);
}
__device__ __forceinline__ float b2f(ushort u) {
    return __uint_as_float((unsigned)u << 16);
}

// async global->LDS, 16B per lane; lds dest must be wave-uniform base (+lane*16 implicit)
__device__ __forceinline__ void gload16(const void* g, void* l) {
    __builtin_amdgcn_global_load_lds((__attribute__((address_space(1))) void*)g,
                                     (__attribute__((address_space(3))) void*)l, 16, 0, 0);
}

// bf16-pair (one dword) elementwise product accumulate: a += (x .* r) * sc
__device__ __forceinline__ void bacc(unsigned xa, unsigned ra, float sc, float2& a) {
    float x0 = __uint_as_float(xa << 16);
    float x1 = __uint_as_float(xa & 0xFFFF0000u);
    float r0 = __uint_as_float(ra << 16);
    float r1 = __uint_as_float(ra & 0xFFFF0000u);
    a.x = fmaf(x0 * r0, sc, a.x);
    a.y = fmaf(x1 * r1, sc, a.y);
}

// ================= CSR build =================
__global__ __launch_bounds__(256) void hist_kernel(const int* __restrict__ ei,
                                                   int* __restrict__ cnt_in,
                                                   int* __restrict__ cnt_out) {
    int e = blockIdx.x * blockDim.x + threadIdx.x;
    if (e >= NE2) return;
    int row = ei[e];
    if (e < EHALF) atomicAdd(&cnt_in[row], 1);
    else           atomicAdd(&cnt_out[row], 1);
}

__global__ __launch_bounds__(256) void scan1_kernel(const int* __restrict__ cnt_in,
                                                    const int* __restrict__ cnt_out,
                                                    int* __restrict__ rp_in, int* __restrict__ rp_out,
                                                    float* __restrict__ dv_in, float* __restrict__ dv_out,
                                                    int* __restrict__ bsum) {
    int half = blockIdx.y;
    const int* cnt = half ? cnt_out : cnt_in;
    int* rp  = half ? rp_out : rp_in;
    float* dv = half ? dv_out : dv_in;
    __shared__ int sm[256];
    int tid = threadIdx.x;
    int base = blockIdx.x * 1024 + tid * 4;
    int v[4];
#pragma unroll
    for (int j = 0; j < 4; ++j) { int i = base + j; v[j] = (i < N_ENT) ? cnt[i] : 0; }
    int tsum = v[0] + v[1] + v[2] + v[3];
    sm[tid] = tsum;
    __syncthreads();
    for (int off = 1; off < 256; off <<= 1) {
        int t = (tid >= off) ? sm[tid - off] : 0;
        __syncthreads();
        sm[tid] += t;
        __syncthreads();
    }
    int run = sm[tid] - tsum;
#pragma unroll
    for (int j = 0; j < 4; ++j) {
        int i = base + j;
        if (i < N_ENT) {
            rp[i] = run;
            dv[i] = v[j] > 0 ? rsqrtf((float)v[j]) : 0.0f;
        }
        run += v[j];
    }
    if (tid == 255) bsum[half * 98 + blockIdx.x] = sm[255];
}

// scan of 98 block sums per half + zero BN stat accumulators
__global__ void scan2_kernel(int* __restrict__ bsum, float* __restrict__ stats) {
    int tid = threadIdx.x;
    stats[tid]       = 0.f;   // colsum
    stats[tid + 256] = 0.f;   // colsumsq
    if (tid < 2) {
        int run = 0;
        for (int b = 0; b < 98; ++b) { int t = bsum[tid * 98 + b]; bsum[tid * 98 + b] = run; run += t; }
    }
}

__global__ __launch_bounds__(256) void scan3_kernel(int* __restrict__ rp_in, int* __restrict__ rp_out,
                                                    int* __restrict__ cnt_in, int* __restrict__ cnt_out,
                                                    const int* __restrict__ bsum) {
    int half = blockIdx.y;
    int* rp  = half ? rp_out : rp_in;
    int* cnt = half ? cnt_out : cnt_in;
    int add = bsum[half * 98 + blockIdx.x];
    int base = blockIdx.x * 1024 + threadIdx.x * 4;
#pragma unroll
    for (int j = 0; j < 4; ++j) {
        int i = base + j;
        if (i < N_ENT) { int t = rp[i] + add; rp[i] = t; cnt[i] = t; }
    }
    if (blockIdx.x == 0 && threadIdx.x == 0) rp[N_ENT] = EHALF;
}

// packed scatter: el[p] = { (col<<8)|type , norm_scale_bits }  (8B records)
__global__ __launch_bounds__(256) void scatterp2_kernel(const int* __restrict__ ei,
                                                        const int* __restrict__ et,
                                                        const float* __restrict__ dv_in,
                                                        const float* __restrict__ dv_out,
                                                        int* __restrict__ cur_in, int* __restrict__ cur_out,
                                                        uint2* __restrict__ el_in, uint2* __restrict__ el_out) {
    int e = blockIdx.x * blockDim.x + threadIdx.x;
    if (e >= NE2) return;
    int row = ei[e];
    int col = ei[NE2 + e];
    unsigned pk = ((unsigned)col << 8) | (unsigned)et[e];
    if (e < EHALF) {
        float sc = dv_in[row] * dv_in[col];
        int p = atomicAdd(&cur_in[row], 1);
        el_in[p] = make_uint2(pk, __float_as_uint(sc));
    } else {
        float sc = dv_out[row] * dv_out[col];
        int p = atomicAdd(&cur_out[row], 1);
        el_out[p] = make_uint2(pk, __float_as_uint(sc));
    }
}

// legacy scatter (mid fallback)
__global__ __launch_bounds__(256) void scatter_kernel(const int* __restrict__ ei,
                                                      int* __restrict__ cur_in, int* __restrict__ cur_out,
                                                      int* __restrict__ el_in, int* __restrict__ el_out) {
    int e = blockIdx.x * blockDim.x + threadIdx.x;
    if (e >= NE2) return;
    int row = ei[e];
    if (e < EHALF) { int p = atomicAdd(&cur_in[row], 1);  el_in[p]  = e; }
    else           { int p = atomicAdd(&cur_out[row], 1); el_out[p] = e; }
}

// ============ prep: x/rel -> bf16, wT build, rel_out GEMM, pad zero ============
#define PB_CONVX  25000              // N_ENT*D/4/256
#define PB_CONVR  (PB_CONVX + 50)    // NREL*D/4/256
#define PB_WCONV  (PB_CONVR + 256)
#define PB_RELG   (PB_WCONV + 200)
#define PB_PADS   (PB_RELG + 72)     // 3 arrays * 24 blocks
__global__ __launch_bounds__(256) void prep_kernel(
        const float* __restrict__ x, const float* __restrict__ rel,
        const float* __restrict__ w_in, const float* __restrict__ w_out,
        const float* __restrict__ w_loop, const float* __restrict__ lrel,
        const float* __restrict__ w_rel,
        ushort* __restrict__ x16, ushort* __restrict__ rel16,
        ushort* __restrict__ wT, float* __restrict__ rel_out,
        ushort* __restrict__ agg_in, ushort* __restrict__ agg_out) {
    int b = blockIdx.x, tid = threadIdx.x;
    if (b < PB_CONVX) {
        int i = b * 256 + tid;
        float4 v = ((const float4*)x)[i];
        ushort4 o; o.x = f2b(v.x); o.y = f2b(v.y); o.z = f2b(v.z); o.w = f2b(v.w);
        ((ushort4*)x16)[i] = o;
    } else if (b < PB_CONVR) {
        int i = (b - PB_CONVX) * 256 + tid;
        float4 v = ((const float4*)rel)[i];
        ushort4 o; o.x = f2b(v.x); o.y = f2b(v.y); o.z = f2b(v.z); o.w = f2b(v.w);
        ((ushort4*)rel16)[i] = o;
    } else if (b < PB_WCONV) {
        int n = b - PB_CONVR;
        int k = tid;
        wT[(size_t)n * 768 + 0   + k] = f2b(w_in [k * 256 + n]);
        wT[(size_t)n * 768 + 256 + k] = f2b(w_out[k * 256 + n]);
        wT[(size_t)n * 768 + 512 + k] = f2b(w_loop[k * 256 + n] * lrel[k]);
    } else if (b < PB_RELG) {
        int r = b - PB_WCONV;
        int c = tid;
        float a = 0.f;
        for (int k = 0; k < 256; ++k)
            a = fmaf(rel[r * 256 + k], w_rel[k * 256 + c], a);
        rel_out[r * 256 + c] = a;
    } else {
        int idx = b - PB_RELG;            // [0,72)
        int arr = idx / 24, blk = idx % 24;
        ushort* base = (arr == 0) ? agg_in : (arr == 1) ? agg_out : x16;
        int i = blk * 256 + tid;          // [0,6144) ushort4s = (MPAD-N_ENT)*D
        ((ushort4*)(base + (size_t)N_ENT * D))[i] = (ushort4){0, 0, 0, 0};
    }
}

// ============ packed bf16 gather aggregation (8B records, lean addr math) ======
__global__ __launch_bounds__(256) void agg2_kernel(
        const int* __restrict__ rp_in, const uint2* __restrict__ el_in, ushort* __restrict__ agg_in,
        const int* __restrict__ rp_out, const uint2* __restrict__ el_out, ushort* __restrict__ agg_out,
        const ushort* __restrict__ x16, const ushort* __restrict__ rel16) {
    int half = blockIdx.y;
    const int*   rp = half ? rp_out  : rp_in;
    const uint2* el = half ? el_out : el_in;
    ushort* agg     = half ? agg_out : agg_in;
    int wid  = (blockIdx.x * blockDim.x + threadIdx.x) >> 6;
    int lane = threadIdx.x & 63;
    if (wid >= N_ENT) return;
    const ushort* xl = x16   + lane * 4;     // lane offset folded into base
    const ushort* rl = rel16 + lane * 4;
    int s = rp[wid], eend = rp[wid + 1];
    float2 a01 = {0.f, 0.f}, a23 = {0.f, 0.f};
    int p = s;
    for (; p + 4 <= eend; p += 4) {
        uint2 r0 = el[p], r1 = el[p + 1], r2 = el[p + 2], r3 = el[p + 3];
        uint2 x0 = *(const uint2*)(xl + (size_t)(r0.x >> 8) * 256);
        uint2 v0 = *(const uint2*)(rl + (size_t)(r0.x & 255u) * 256);
        uint2 x1 = *(const uint2*)(xl + (size_t)(r1.x >> 8) * 256);
        uint2 v1 = *(const uint2*)(rl + (size_t)(r1.x & 255u) * 256);
        uint2 x2 = *(const uint2*)(xl + (size_t)(r2.x >> 8) * 256);
        uint2 v2 = *(const uint2*)(rl + (size_t)(r2.x & 255u) * 256);
        uint2 x3 = *(const uint2*)(xl + (size_t)(r3.x >> 8) * 256);
        uint2 v3 = *(const uint2*)(rl + (size_t)(r3.x & 255u) * 256);
        float s0 = __uint_as_float(r0.y), s1 = __uint_as_float(r1.y);
        float s2 = __uint_as_float(r2.y), s3 = __uint_as_float(r3.y);
        bacc(x0.x, v0.x, s0, a01); bacc(x0.y, v0.y, s0, a23);
        bacc(x1.x, v1.x, s1, a01); bacc(x1.y, v1.y, s1, a23);
        bacc(x2.x, v2.x, s2, a01); bacc(x2.y, v2.y, s2, a23);
        bacc(x3.x, v3.x, s3, a01); bacc(x3.y, v3.y, s3, a23);
    }
    for (; p < eend; ++p) {
        uint2 rr = el[p];
        uint2 xv = *(const uint2*)(xl + (size_t)(rr.x >> 8) * 256);
        uint2 rv = *(const uint2*)(rl + (size_t)(rr.x & 255u) * 256);
        float sc = __uint_as_float(rr.y);
        bacc(xv.x, rv.x, sc, a01); bacc(xv.y, rv.y, sc, a23);
    }
    ushort4 o;
    o.x = f2b(a01.x); o.y = f2b(a01.y); o.z = f2b(a23.x); o.w = f2b(a23.y);
    *(ushort4*)(agg + (size_t)wid * D + lane * 4) = o;
}

// ============ legacy f32-x aggregation (mid fallback) ============
__global__ __launch_bounds__(256) void agg_csr16_kernel(
        const int* __restrict__ rp, const int* __restrict__ elist,
        const int* __restrict__ colidx, const int* __restrict__ et,
        const float* __restrict__ dinv, const float* __restrict__ x,
        const float* __restrict__ rel, ushort* __restrict__ agg) {
    int wid  = (blockIdx.x * blockDim.x + threadIdx.x) >> 6;
    int lane = threadIdx.x & 63;
    if (wid >= N_ENT) return;
    int s = rp[wid], eend = rp[wid + 1];
    float dr = dinv[wid];
    float4 acc = make_float4(0.f, 0.f, 0.f, 0.f);
    int e = (s < eend) ? elist[s] : 0;
    for (int p = s; p < eend; ++p) {
        int c = colidx[e];
        int t = et[e];
        int enext = (p + 1 < eend) ? elist[p + 1] : 0;
        float sc = dr * dinv[c];
        float4 xv = *(const float4*)(x   + (size_t)c * D + lane * 4);
        float4 rv = *(const float4*)(rel + (size_t)t * D + lane * 4);
        acc.x = fmaf(xv.x * rv.x, sc, acc.x);
        acc.y = fmaf(xv.y * rv.y, sc, acc.y);
        acc.z = fmaf(xv.z * rv.z, sc, acc.z);
        acc.w = fmaf(xv.w * rv.w, sc, acc.w);
        e = enext;
    }
    ushort4 o;
    o.x = f2b(acc.x); o.y = f2b(acc.y); o.z = f2b(acc.z); o.w = f2b(acc.w);
    *(ushort4*)(agg + (size_t)wid * D + lane * 4) = o;
}

// mid-fallback weight transpose (no lrel fold)
__global__ __launch_bounds__(256) void wconv_kernel(const float* __restrict__ w_in,
                                                    const float* __restrict__ w_out,
                                                    const float* __restrict__ w_loop,
                                                    ushort* __restrict__ wT) {
    int n = blockIdx.x;
    int k = threadIdx.x;
    wT[(size_t)n * 768 + 0   + k] = f2b(w_in [k * 256 + n]);
    wT[(size_t)n * 768 + 256 + k] = f2b(w_out[k * 256 + n]);
    wT[(size_t)n * 768 + 512 + k] = f2b(w_loop[k * 256 + n]);
}

// ============ m97-style fused GEMM: C = [Ain|Aout|x16] @ wT^T (+BN partials) ====
// 128x128 tile, BK=32, linear LDS [128][32], global_load_lds w16 staging
__global__ __launch_bounds__(256) void fused_gemm2_kernel(
        const ushort* __restrict__ Ain, const ushort* __restrict__ Aout,
        const ushort* __restrict__ X16p, const ushort* __restrict__ wT,
        float* __restrict__ C, float* __restrict__ colsum, float* __restrict__ colsumsq) {
    __shared__ ushort As[2][128 * 32];
    __shared__ ushort Bs[2][128 * 32];
    int tid  = threadIdx.x;
    int row0 = blockIdx.x * 128;
    int col0 = blockIdx.y * 128;
    int w    = tid >> 6, lane = tid & 63;
    int wr   = w >> 1,  wc = w & 1;
    int r16  = lane & 15, kg = lane >> 4;

    f32x4 acc[4][4];
#pragma unroll
    for (int mi = 0; mi < 4; ++mi)
#pragma unroll
        for (int ni = 0; ni < 4; ++ni)
            acc[mi][ni] = (f32x4){0.f, 0.f, 0.f, 0.f};

    // granule geometry: per round r (0/1), granule gi = r*256 + tid; row = gi>>2,
    // g = gi&3 (16B granules within the row's 64B K-slice). LDS dest linear: gi*16B.
    int grow0 = tid >> 2, gg0 = tid & 3;                 // round 0
    int grow1 = (256 + tid) >> 2, gg1 = tid & 3;         // round 1

    auto stage = [&](int kt, int buf) {
        int k0 = kt * 32;
        int seg = kt >> 3;
        const ushort* Abase = (seg == 0) ? Ain : (seg == 1) ? Aout : X16p;
        int ka = k0 & 255;
        gload16(Abase + (size_t)(row0 + grow0) * 256 + ka + gg0 * 8,
                (char*)&As[buf][0] + (size_t)(w * 64) * 16);
        gload16(Abase + (size_t)(row0 + grow1) * 256 + ka + gg1 * 8,
                (char*)&As[buf][0] + (size_t)(256 + w * 64) * 16);
        gload16(wT + (size_t)(col0 + grow0) * 768 + k0 + gg0 * 8,
                (char*)&Bs[buf][0] + (size_t)(w * 64) * 16);
        gload16(wT + (size_t)(col0 + grow1) * 768 + k0 + gg1 * 8,
                (char*)&Bs[buf][0] + (size_t)(256 + w * 64) * 16);
    };

    stage(0, 0);
    __syncthreads();
    for (int kt = 0; kt < 24; ++kt) {
        int cur = kt & 1;
        if (kt + 1 < 24) stage(kt + 1, cur ^ 1);
        bf16x8 af[4], bfr[4];
#pragma unroll
        for (int i = 0; i < 4; ++i) {
            af[i]  = *(const bf16x8*)&As[cur][(wr * 64 + i * 16 + r16) * 32 + kg * 8];
            bfr[i] = *(const bf16x8*)&Bs[cur][(wc * 64 + i * 16 + r16) * 32 + kg * 8];
        }
#pragma unroll
        for (int mi = 0; mi < 4; ++mi)
#pragma unroll
            for (int ni = 0; ni < 4; ++ni)
                acc[mi][ni] = __builtin_amdgcn_mfma_f32_16x16x32_bf16(af[mi], bfr[ni], acc[mi][ni], 0, 0, 0);
        __syncthreads();
    }

#pragma unroll
    for (int mi = 0; mi < 4; ++mi) {
        int r = row0 + wr * 64 + mi * 16 + kg * 4;
#pragma unroll
        for (int ni = 0; ni < 4; ++ni) {
            int c = col0 + wc * 64 + ni * 16 + r16;
#pragma unroll
            for (int j = 0; j < 4; ++j) {
                int rr = r + j;
                if (rr < N_ENT) C[(size_t)rr * 256 + c] = acc[mi][ni][j];
            }
        }
    }

    // BN raw partial sums (pad rows are zeroed -> contribute 0)
#pragma unroll
    for (int ni = 0; ni < 4; ++ni) {
        float s = 0.f, ss = 0.f;
#pragma unroll
        for (int mi = 0; mi < 4; ++mi)
#pragma unroll
            for (int j = 0; j < 4; ++j) {
                float v = acc[mi][ni][j];
                s += v; ss += v * v;
            }
        s += __shfl_xor(s, 16); ss += __shfl_xor(ss, 16);
        s += __shfl_xor(s, 32); ss += __shfl_xor(ss, 32);
        if (kg == 0) {
            int c = col0 + wc * 64 + ni * 16 + r16;
            atomicAdd(&colsum[c], s);
            atomicAdd(&colsumsq[c], ss);
        }
    }
}

// ============ fallback GEMM (reg-staged, f32-x conversion inline) ============
__global__ __launch_bounds__(256) void fused_gemm_fb_kernel(
        const ushort* __restrict__ Ain, const ushort* __restrict__ Aout,
        const float* __restrict__ xf, const float* __restrict__ lrel,
        const ushort* __restrict__ wT, float* __restrict__ C) {
    __shared__ ushort As[2][128 * 40];
    __shared__ ushort Bs[2][128 * 40];
    int tid  = threadIdx.x;
    int row0 = blockIdx.x * 128;
    int col0 = blockIdx.y * 128;
    int srow = tid >> 1, hb = tid & 1;
    int w    = tid >> 6, lane = tid & 63;
    int wr   = w >> 1,  wc = w & 1;
    int r16  = lane & 15, kg = lane >> 4;

    f32x4 acc[4][4];
#pragma unroll
    for (int mi = 0; mi < 4; ++mi)
#pragma unroll
        for (int ni = 0; ni < 4; ++ni)
            acc[mi][ni] = (f32x4){0.f, 0.f, 0.f, 0.f};

    auto stage = [&](int kt, int buf) {
        int k0 = kt * 32;
        int seg = k0 >> 8;
        int kl  = (k0 & 255) + hb * 16;
        ushort* Ad = &As[buf][srow * 40 + hb * 16];
        if (seg < 2) {
            const ushort* src = (seg ? Aout : Ain) + (size_t)(row0 + srow) * 256 + kl;
            *(us8*)Ad       = *(const us8*)src;
            *(us8*)(Ad + 8) = *(const us8*)(src + 8);
        } else {
            int gr = row0 + srow;
            us8 pa, pb;
            if (gr < N_ENT) {
                const float* src = xf + (size_t)gr * 256 + kl;
                const float* ls  = lrel + kl;
#pragma unroll
                for (int j = 0; j < 8; ++j) {
                    pa[j] = (short)f2b(src[j] * ls[j]);
                    pb[j] = (short)f2b(src[8 + j] * ls[8 + j]);
                }
            } else {
#pragma unroll
                for (int j = 0; j < 8; ++j) { pa[j] = 0; pb[j] = 0; }
            }
            *(us8*)Ad       = pa;
            *(us8*)(Ad + 8) = pb;
        }
        ushort* Bd = &Bs[buf][srow * 40 + hb * 16];
        const ushort* bsrc = wT + (size_t)(col0 + srow) * 768 + k0 + hb * 16;
        *(us8*)Bd       = *(const us8*)bsrc;
        *(us8*)(Bd + 8) = *(const us8*)(bsrc + 8);
    };

    stage(0, 0);
    __syncthreads();
    for (int kt = 0; kt < 24; ++kt) {
        int cur = kt & 1;
        if (kt + 1 < 24) stage(kt + 1, cur ^ 1);
        const ushort* Ab = &As[cur][(wr * 64 + r16) * 40 + kg * 8];
        const ushort* Bb = &Bs[cur][(wc * 64 + r16) * 40 + kg * 8];
        bf16x8 af[4], bfr[4];
#pragma unroll
        for (int i = 0; i < 4; ++i) {
            af[i]  = *(const bf16x8*)(Ab + i * 640);
            bfr[i] = *(const bf16x8*)(Bb + i * 640);
        }
#pragma unroll
        for (int mi = 0; mi < 4; ++mi)
#pragma unroll
            for (int ni = 0; ni < 4; ++ni)
                acc[mi][ni] = __builtin_amdgcn_mfma_f32_16x16x32_bf16(af[mi], bfr[ni], acc[mi][ni], 0, 0, 0);
        __syncthreads();
    }

#pragma unroll
    for (int mi = 0; mi < 4; ++mi) {
        int r = row0 + wr * 64 + mi * 16 + kg * 4;
#pragma unroll
        for (int ni = 0; ni < 4; ++ni) {
            int c = col0 + wc * 64 + ni * 16 + r16;
#pragma unroll
            for (int j = 0; j < 4; ++j) {
                int rr = r + j;
                if (rr < N_ENT) C[(size_t)rr * 256 + c] = acc[mi][ni][j];
            }
        }
    }
}

// ---------------- BatchNorm ----------------
__global__ __launch_bounds__(256) void bn_stats_kernel(
        const float* __restrict__ out, const float* __restrict__ bias,
        float* __restrict__ colsum, float* __restrict__ colsumsq) {
    int c  = threadIdx.x;
    int r0 = blockIdx.x * 64;
    float b = bias[c];
    float s = 0.f, sq = 0.f;
    int rend = min(r0 + 64, N_ENT);
    for (int r = r0; r < rend; ++r) {
        float v = out[(size_t)r * 256 + c] * (1.f / 3.f) + b;
        s += v; sq += v * v;
    }
    atomicAdd(&colsum[c], s);
    atomicAdd(&colsumsq[c], sq);
}

template<bool RAW>
__global__ void bn_finalize_kernel(const float* __restrict__ colsum, const float* __restrict__ colsumsq,
                                   const float* __restrict__ bias, const float* __restrict__ gamma,
                                   const float* __restrict__ beta,
                                   float* __restrict__ colA, float* __restrict__ colB) {
    int c = threadIdx.x;
    float invN = 1.f / N_ENT;
    float mean, var;
    if (RAW) {
        float Er  = colsum[c] * invN;
        float Er2 = colsumsq[c] * invN;
        float b = bias[c];
        mean = Er * (1.f / 3.f) + b;
        var  = Er2 * (1.f / 9.f) + 2.f * b * Er * (1.f / 3.f) + b * b - mean * mean;
    } else {
        mean = colsum[c] * invN;
        var  = colsumsq[c] * invN - mean * mean;
    }
    float sc = rsqrtf(var + BN_EPS) * gamma[c];
    colA[c] = sc * (1.f / 3.f);
    colB[c] = (bias[c] - mean) * sc + beta[c];
}

__global__ __launch_bounds__(256) void bn_apply_kernel(
        float* __restrict__ out, const float* __restrict__ colA, const float* __restrict__ colB) {
    size_t i4 = (size_t)blockIdx.x * 256 + threadIdx.x;
    float4 v = ((const float4*)out)[i4];
    int c4 = (int)(i4 & 63) * 4;
    v.x = v.x * colA[c4 + 0] + colB[c4 + 0];
    v.y = v.y * colA[c4 + 1] + colB[c4 + 1];
    v.z = v.z * colA[c4 + 2] + colB[c4 + 2];
    v.w = v.w * colA[c4 + 3] + colB[c4 + 3];
    ((float4*)out)[i4] = v;
}

__global__ __launch_bounds__(256) void relgemm_kernel(
        const float* __restrict__ rel, const float* __restrict__ w, float* __restrict__ out) {
    int r = blockIdx.x;
    int c = threadIdx.x;
    float acc = 0.f;
    for (int k = 0; k < 256; ++k)
        acc = fmaf(rel[r * 256 + k], w[k * 256 + c], acc);
    out[r * 256 + c] = acc;
}

extern "C" void kernel_launch(void* const* d_in, const int* in_sizes, int n_in,
                              void* d_out, int out_size, void* d_ws, size_t ws_size,
                              hipStream_t stream) {
    const float* x        = (const float*)d_in[0];
    const int*   ei       = (const int*)d_in[1];
    const int*   et       = (const int*)d_in[2];
    const float* rel      = (const float*)d_in[3];
    const float* w_loop   = (const float*)d_in[4];
    const float* w_in     = (const float*)d_in[5];
    const float* w_out    = (const float*)d_in[6];
    const float* w_rel    = (const float*)d_in[7];
    const float* loop_rel = (const float*)d_in[8];
    const float* bias     = (const float*)d_in[9];
    const float* gamma    = (const float*)d_in[10];
    const float* beta     = (const float*)d_in[11];

    float* out     = (float*)d_out;
    float* rel_out = out + (size_t)N_ENT * D;
    const int* colidx = ei + NE2;

    // ---- workspace layout (full path) ----
    char* ws = (char*)d_ws;
    size_t off = 0;
    ushort* agg_in16  = (ushort*)(ws + off); off += (size_t)MPAD * D * 2;
    ushort* agg_out16 = (ushort*)(ws + off); off += (size_t)MPAD * D * 2;
    int* rp_in   = (int*)(ws + off); off += 400416;
    int* rp_out  = (int*)(ws + off); off += 400416;
    float* dv_in  = (float*)(ws + off); off += 400416;
    float* dv_out = (float*)(ws + off); off += 400416;
    uint2* el2_in  = (uint2*)(ws + off); off += (size_t)EHALF * 8;
    uint2* el2_out = (uint2*)(ws + off); off += (size_t)EHALF * 8;
    ushort* wT  = (ushort*)(ws + off); off += 768 * 256 * 2;
    float* stats = (float*)(ws + off); off += 8192;
    ushort* x16   = (ushort*)(ws + off); off += (size_t)MPAD * D * 2;
    ushort* rel16 = (ushort*)(ws + off); off += (size_t)NREL * D * 2;
    size_t needed_full = off;

    float* colsum = stats, *colsumsq = stats + 256;
    float* colA = stats + 512, *colB = stats + 768;
    int* bsum = (int*)(stats + 1024);
    int* cnt_in  = (int*)agg_in16;            // dead before agg written
    int* cnt_out = cnt_in + 100004;

    if (ws_size >= needed_full) {
        // ======== full path ========
        hipMemsetAsync(cnt_in, 0, 2 * 100004 * 4, stream);

        hist_kernel<<<(NE2 + 255) / 256, 256, 0, stream>>>(ei, cnt_in, cnt_out);
        scan1_kernel<<<dim3(98, 2), 256, 0, stream>>>(cnt_in, cnt_out, rp_in, rp_out, dv_in, dv_out, bsum);
        scan2_kernel<<<1, 256, 0, stream>>>(bsum, stats);
        scan3_kernel<<<dim3(98, 2), 256, 0, stream>>>(rp_in, rp_out, cnt_in, cnt_out, bsum);
        scatterp2_kernel<<<(NE2 + 255) / 256, 256, 0, stream>>>(ei, et, dv_in, dv_out,
                                                                cnt_in, cnt_out, el2_in, el2_out);
        prep_kernel<<<PB_PADS, 256, 0, stream>>>(x, rel, w_in, w_out, w_loop, loop_rel, w_rel,
                                                 x16, rel16, wT, rel_out, agg_in16, agg_out16);

        agg2_kernel<<<dim3((N_ENT * 64 + 255) / 256, 2), 256, 0, stream>>>(
            rp_in, el2_in, agg_in16, rp_out, el2_out, agg_out16, x16, rel16);

        fused_gemm2_kernel<<<dim3(MPAD / 128, 2), 256, 0, stream>>>(
            agg_in16, agg_out16, x16, wT, out, colsum, colsumsq);

        bn_finalize_kernel<true><<<1, 256, 0, stream>>>(colsum, colsumsq, bias, gamma, beta, colA, colB);
        bn_apply_kernel<<<(N_ENT * 64) / 256, 256, 0, stream>>>(out, colA, colB);
    } else {
        // ======== mid fallback: f32 gathers, separate bn_stats ========
        int* el_in  = (int*)el2_in;
        int* el_out = el_in + EHALF;
        hipMemsetAsync(cnt_in, 0, 2 * 100004 * 4, stream);
        hist_kernel<<<(NE2 + 255) / 256, 256, 0, stream>>>(ei, cnt_in, cnt_out);
        scan1_kernel<<<dim3(98, 2), 256, 0, stream>>>(cnt_in, cnt_out, rp_in, rp_out, dv_in, dv_out, bsum);
        scan2_kernel<<<1, 256, 0, stream>>>(bsum, stats);
        scan3_kernel<<<dim3(98, 2), 256, 0, stream>>>(rp_in, rp_out, cnt_in, cnt_out, bsum);
        scatter_kernel<<<(NE2 + 255) / 256, 256, 0, stream>>>(ei, cnt_in, cnt_out, el_in, el_out);
        wconv_kernel<<<256, 256, 0, stream>>>(w_in, w_out, w_loop, wT);

        agg_csr16_kernel<<<(N_ENT * 64 + 255) / 256, 256, 0, stream>>>(
            rp_in, el_in, colidx, et, dv_in, x, rel, agg_in16);
        agg_csr16_kernel<<<(N_ENT * 64 + 255) / 256, 256, 0, stream>>>(
            rp_out, el_out, colidx, et, dv_out, x, rel, agg_out16);

        fused_gemm_fb_kernel<<<dim3(MPAD / 128, 2), 256, 0, stream>>>(
            agg_in16, agg_out16, x, loop_rel, wT, out);

        bn_stats_kernel<<<(N_ENT + 63) / 64, 256, 0, stream>>>(out, bias, colsum, colsumsq);
        bn_finalize_kernel<false><<<1, 256, 0, stream>>>(colsum, colsumsq, bias, gamma, beta, colA, colB);
        bn_apply_kernel<<<(N_ENT * 64) / 256, 256, 0, stream>>>(out, colA, colB);
        relgemm_kernel<<<NREL, 256, 0, stream>>>(rel, w_rel, rel_out);
    }
}

// Round 8
// 416.906 us; speedup vs baseline: 9.7464x; 1.0075x over previous
//
#include <hip/hip_runtime.h>

#define N_ENT  100000
#define MPAD   100096           // 782 * 128
#define EHALF  500000
#define NE2    1000000
#define D      256
#define NREL   200
#define BN_EPS 1e-5f

typedef __attribute__((ext_vector_type(8))) short  bf16x8;
typedef __attribute__((ext_vector_type(8))) ushort us8;
typedef __attribute__((ext_vector_type(4))) float  f32x4;

__device__ __forceinline__ ushort f2b(float f) {
    unsigned u = __float_as_uint(f);
    return (ushort)((u + 0x7fffu + ((u >> 16) & 1u)) >> 16);
}
__device__ __forceinline__ float b2f(ushort u) {
    return __uint_as_float((unsigned)u << 16);
}

// async global->LDS, 16B per lane; lds dest must be wave-uniform base (+lane*16 implicit)
__device__ __forceinline__ void gload16(const void* g, void* l) {
    __builtin_amdgcn_global_load_lds((__attribute__((address_space(1))) void*)g,
                                     (__attribute__((address_space(3))) void*)l, 16, 0, 0);
}

// bf16-pair (one dword) elementwise product accumulate: a += (x .* r) * sc
__device__ __forceinline__ void bacc(unsigned xa, unsigned ra, float sc, float2& a) {
    float x0 = __uint_as_float(xa << 16);
    float x1 = __uint_as_float(xa & 0xFFFF0000u);
    float r0 = __uint_as_float(ra << 16);
    float r1 = __uint_as_float(ra & 0xFFFF0000u);
    a.x = fmaf(x0 * r0, sc, a.x);
    a.y = fmaf(x1 * r1, sc, a.y);
}

// ================= CSR build =================
__global__ __launch_bounds__(256) void hist_kernel(const int* __restrict__ ei,
                                                   int* __restrict__ cnt_in,
                                                   int* __restrict__ cnt_out) {
    int e = blockIdx.x * blockDim.x + threadIdx.x;
    if (e >= NE2) return;
    int row = ei[e];
    if (e < EHALF) atomicAdd(&cnt_in[row], 1);
    else           atomicAdd(&cnt_out[row], 1);
}

__global__ __launch_bounds__(256) void scan1_kernel(const int* __restrict__ cnt_in,
                                                    const int* __restrict__ cnt_out,
                                                    int* __restrict__ rp_in, int* __restrict__ rp_out,
                                                    float* __restrict__ dv_in, float* __restrict__ dv_out,
                                                    int* __restrict__ bsum) {
    int half = blockIdx.y;
    const int* cnt = half ? cnt_out : cnt_in;
    int* rp  = half ? rp_out : rp_in;
    float* dv = half ? dv_out : dv_in;
    __shared__ int sm[256];
    int tid = threadIdx.x;
    int base = blockIdx.x * 1024 + tid * 4;
    int v[4];
#pragma unroll
    for (int j = 0; j < 4; ++j) { int i = base + j; v[j] = (i < N_ENT) ? cnt[i] : 0; }
    int tsum = v[0] + v[1] + v[2] + v[3];
    sm[tid] = tsum;
    __syncthreads();
    for (int off = 1; off < 256; off <<= 1) {
        int t = (tid >= off) ? sm[tid - off] : 0;
        __syncthreads();
        sm[tid] += t;
        __syncthreads();
    }
    int run = sm[tid] - tsum;
#pragma unroll
    for (int j = 0; j < 4; ++j) {
        int i = base + j;
        if (i < N_ENT) {
            rp[i] = run;
            dv[i] = v[j] > 0 ? rsqrtf((float)v[j]) : 0.0f;
        }
        run += v[j];
    }
    if (tid == 255) bsum[half * 98 + blockIdx.x] = sm[255];
}

// scan of 98 block sums per half + zero BN stat accumulators
__global__ void scan2_kernel(int* __restrict__ bsum, float* __restrict__ stats) {
    int tid = threadIdx.x;
    stats[tid]       = 0.f;   // colsum
    stats[tid + 256] = 0.f;   // colsumsq
    if (tid < 2) {
        int run = 0;
        for (int b = 0; b < 98; ++b) { int t = bsum[tid * 98 + b]; bsum[tid * 98 + b] = run; run += t; }
    }
}

__global__ __launch_bounds__(256) void scan3_kernel(int* __restrict__ rp_in, int* __restrict__ rp_out,
                                                    int* __restrict__ cnt_in, int* __restrict__ cnt_out,
                                                    const int* __restrict__ bsum) {
    int half = blockIdx.y;
    int* rp  = half ? rp_out : rp_in;
    int* cnt = half ? cnt_out : cnt_in;
    int add = bsum[half * 98 + blockIdx.x];
    int base = blockIdx.x * 1024 + threadIdx.x * 4;
#pragma unroll
    for (int j = 0; j < 4; ++j) {
        int i = base + j;
        if (i < N_ENT) { int t = rp[i] + add; rp[i] = t; cnt[i] = t; }
    }
    if (blockIdx.x == 0 && threadIdx.x == 0) rp[N_ENT] = EHALF;
}

// packed scatter: el[p] = { (col<<8)|type , norm_scale_bits }  (8B records)
__global__ __launch_bounds__(256) void scatterp2_kernel(const int* __restrict__ ei,
                                                        const int* __restrict__ et,
                                                        const float* __restrict__ dv_in,
                                                        const float* __restrict__ dv_out,
                                                        int* __restrict__ cur_in, int* __restrict__ cur_out,
                                                        uint2* __restrict__ el_in, uint2* __restrict__ el_out) {
    int e = blockIdx.x * blockDim.x + threadIdx.x;
    if (e >= NE2) return;
    int row = ei[e];
    int col = ei[NE2 + e];
    unsigned pk = ((unsigned)col << 8) | (unsigned)et[e];
    if (e < EHALF) {
        float sc = dv_in[row] * dv_in[col];
        int p = atomicAdd(&cur_in[row], 1);
        el_in[p] = make_uint2(pk, __float_as_uint(sc));
    } else {
        float sc = dv_out[row] * dv_out[col];
        int p = atomicAdd(&cur_out[row], 1);
        el_out[p] = make_uint2(pk, __float_as_uint(sc));
    }
}

// legacy scatter (mid fallback)
__global__ __launch_bounds__(256) void scatter_kernel(const int* __restrict__ ei,
                                                      int* __restrict__ cur_in, int* __restrict__ cur_out,
                                                      int* __restrict__ el_in, int* __restrict__ el_out) {
    int e = blockIdx.x * blockDim.x + threadIdx.x;
    if (e >= NE2) return;
    int row = ei[e];
    if (e < EHALF) { int p = atomicAdd(&cur_in[row], 1);  el_in[p]  = e; }
    else           { int p = atomicAdd(&cur_out[row], 1); el_out[p] = e; }
}

// ============ prep: x/rel -> bf16, wT build, rel_out GEMM, pad zero ============
#define PB_CONVX  25000              // N_ENT*D/4/256
#define PB_CONVR  (PB_CONVX + 50)    // NREL*D/4/256
#define PB_WCONV  (PB_CONVR + 256)
#define PB_RELG   (PB_WCONV + 200)
#define PB_PADS   (PB_RELG + 72)     // 3 arrays * 24 blocks
__global__ __launch_bounds__(256) void prep_kernel(
        const float* __restrict__ x, const float* __restrict__ rel,
        const float* __restrict__ w_in, const float* __restrict__ w_out,
        const float* __restrict__ w_loop, const float* __restrict__ lrel,
        const float* __restrict__ w_rel,
        ushort* __restrict__ x16, ushort* __restrict__ rel16,
        ushort* __restrict__ wT, float* __restrict__ rel_out,
        ushort* __restrict__ agg_in, ushort* __restrict__ agg_out) {
    int b = blockIdx.x, tid = threadIdx.x;
    if (b < PB_CONVX) {
        int i = b * 256 + tid;
        float4 v = ((const float4*)x)[i];
        ushort4 o; o.x = f2b(v.x); o.y = f2b(v.y); o.z = f2b(v.z); o.w = f2b(v.w);
        ((ushort4*)x16)[i] = o;
    } else if (b < PB_CONVR) {
        int i = (b - PB_CONVX) * 256 + tid;
        float4 v = ((const float4*)rel)[i];
        ushort4 o; o.x = f2b(v.x); o.y = f2b(v.y); o.z = f2b(v.z); o.w = f2b(v.w);
        ((ushort4*)rel16)[i] = o;
    } else if (b < PB_WCONV) {
        int n = b - PB_CONVR;
        int k = tid;
        wT[(size_t)n * 768 + 0   + k] = f2b(w_in [k * 256 + n]);
        wT[(size_t)n * 768 + 256 + k] = f2b(w_out[k * 256 + n]);
        wT[(size_t)n * 768 + 512 + k] = f2b(w_loop[k * 256 + n] * lrel[k]);
    } else if (b < PB_RELG) {
        int r = b - PB_WCONV;
        int c = tid;
        float a = 0.f;
        for (int k = 0; k < 256; ++k)
            a = fmaf(rel[r * 256 + k], w_rel[k * 256 + c], a);
        rel_out[r * 256 + c] = a;
    } else {
        int idx = b - PB_RELG;            // [0,72)
        int arr = idx / 24, blk = idx % 24;
        ushort* base = (arr == 0) ? agg_in : (arr == 1) ? agg_out : x16;
        int i = blk * 256 + tid;          // [0,6144) ushort4s = (MPAD-N_ENT)*D
        ((ushort4*)(base + (size_t)N_ENT * D))[i] = (ushort4){0, 0, 0, 0};
    }
}

// ============ packed bf16 gather aggregation (8B records, lean addr math) ======
__global__ __launch_bounds__(256) void agg2_kernel(
        const int* __restrict__ rp_in, const uint2* __restrict__ el_in, ushort* __restrict__ agg_in,
        const int* __restrict__ rp_out, const uint2* __restrict__ el_out, ushort* __restrict__ agg_out,
        const ushort* __restrict__ x16, const ushort* __restrict__ rel16) {
    int half = blockIdx.y;
    const int*   rp = half ? rp_out  : rp_in;
    const uint2* el = half ? el_out : el_in;
    ushort* agg     = half ? agg_out : agg_in;
    int wid  = (blockIdx.x * blockDim.x + threadIdx.x) >> 6;
    int lane = threadIdx.x & 63;
    if (wid >= N_ENT) return;
    const ushort* xl = x16   + lane * 4;     // lane offset folded into base
    const ushort* rl = rel16 + lane * 4;
    int s = rp[wid], eend = rp[wid + 1];
    float2 a01 = {0.f, 0.f}, a23 = {0.f, 0.f};
    int p = s;
    for (; p + 4 <= eend; p += 4) {
        uint2 r0 = el[p], r1 = el[p + 1], r2 = el[p + 2], r3 = el[p + 3];
        uint2 x0 = *(const uint2*)(xl + (size_t)(r0.x >> 8) * 256);
        uint2 v0 = *(const uint2*)(rl + (size_t)(r0.x & 255u) * 256);
        uint2 x1 = *(const uint2*)(xl + (size_t)(r1.x >> 8) * 256);
        uint2 v1 = *(const uint2*)(rl + (size_t)(r1.x & 255u) * 256);
        uint2 x2 = *(const uint2*)(xl + (size_t)(r2.x >> 8) * 256);
        uint2 v2 = *(const uint2*)(rl + (size_t)(r2.x & 255u) * 256);
        uint2 x3 = *(const uint2*)(xl + (size_t)(r3.x >> 8) * 256);
        uint2 v3 = *(const uint2*)(rl + (size_t)(r3.x & 255u) * 256);
        float s0 = __uint_as_float(r0.y), s1 = __uint_as_float(r1.y);
        float s2 = __uint_as_float(r2.y), s3 = __uint_as_float(r3.y);
        bacc(x0.x, v0.x, s0, a01); bacc(x0.y, v0.y, s0, a23);
        bacc(x1.x, v1.x, s1, a01); bacc(x1.y, v1.y, s1, a23);
        bacc(x2.x, v2.x, s2, a01); bacc(x2.y, v2.y, s2, a23);
        bacc(x3.x, v3.x, s3, a01); bacc(x3.y, v3.y, s3, a23);
    }
    for (; p < eend; ++p) {
        uint2 rr = el[p];
        uint2 xv = *(const uint2*)(xl + (size_t)(rr.x >> 8) * 256);
        uint2 rv = *(const uint2*)(rl + (size_t)(rr.x & 255u) * 256);
        float sc = __uint_as_float(rr.y);
        bacc(xv.x, rv.x, sc, a01); bacc(xv.y, rv.y, sc, a23);
    }
    ushort4 o;
    o.x = f2b(a01.x); o.y = f2b(a01.y); o.z = f2b(a23.x); o.w = f2b(a23.y);
    *(ushort4*)(agg + (size_t)wid * D + lane * 4) = o;
}

// ============ legacy f32-x aggregation (mid fallback) ============
__global__ __launch_bounds__(256) void agg_csr16_kernel(
        const int* __restrict__ rp, const int* __restrict__ elist,
        const int* __restrict__ colidx, const int* __restrict__ et,
        const float* __restrict__ dinv, const float* __restrict__ x,
        const float* __restrict__ rel, ushort* __restrict__ agg) {
    int wid  = (blockIdx.x * blockDim.x + threadIdx.x) >> 6;
    int lane = threadIdx.x & 63;
    if (wid >= N_ENT) return;
    int s = rp[wid], eend = rp[wid + 1];
    float dr = dinv[wid];
    float4 acc = make_float4(0.f, 0.f, 0.f, 0.f);
    int e = (s < eend) ? elist[s] : 0;
    for (int p = s; p < eend; ++p) {
        int c = colidx[e];
        int t = et[e];
        int enext = (p + 1 < eend) ? elist[p + 1] : 0;
        float sc = dr * dinv[c];
        float4 xv = *(const float4*)(x   + (size_t)c * D + lane * 4);
        float4 rv = *(const float4*)(rel + (size_t)t * D + lane * 4);
        acc.x = fmaf(xv.x * rv.x, sc, acc.x);
        acc.y = fmaf(xv.y * rv.y, sc, acc.y);
        acc.z = fmaf(xv.z * rv.z, sc, acc.z);
        acc.w = fmaf(xv.w * rv.w, sc, acc.w);
        e = enext;
    }
    ushort4 o;
    o.x = f2b(acc.x); o.y = f2b(acc.y); o.z = f2b(acc.z); o.w = f2b(acc.w);
    *(ushort4*)(agg + (size_t)wid * D + lane * 4) = o;
}

// mid-fallback weight transpose (no lrel fold)
__global__ __launch_bounds__(256) void wconv_kernel(const float* __restrict__ w_in,
                                                    const float* __restrict__ w_out,
                                                    const float* __restrict__ w_loop,
                                                    ushort* __restrict__ wT) {
    int n = blockIdx.x;
    int k = threadIdx.x;
    wT[(size_t)n * 768 + 0   + k] = f2b(w_in [k * 256 + n]);
    wT[(size_t)n * 768 + 256 + k] = f2b(w_out[k * 256 + n]);
    wT[(size_t)n * 768 + 512 + k] = f2b(w_loop[k * 256 + n]);
}

// ============ deep-prefetch fused GEMM: C = [Ain|Aout|x16] @ wT^T (+BN) ========
// 128x128 tile, BK=32, 4-buffer LDS ring, prefetch depth 3, counted vmcnt,
// granule XOR-swizzle (pre-swizzled global source + swizzled ds_read).
__global__ __launch_bounds__(256) void fused_gemm3_kernel(
        const ushort* __restrict__ Ain, const ushort* __restrict__ Aout,
        const ushort* __restrict__ X16p, const ushort* __restrict__ wT,
        float* __restrict__ C, float* __restrict__ colsum, float* __restrict__ colsumsq) {
    __shared__ ushort As[4][128 * 32];
    __shared__ ushort Bs[4][128 * 32];
    int tid  = threadIdx.x;
    int row0 = blockIdx.x * 128;
    int col0 = blockIdx.y * 128;
    int w    = tid >> 6, lane = tid & 63;
    int wr   = w >> 1,  wc = w & 1;
    int r16  = lane & 15, kg = lane >> 4;
    int kgS  = (kg ^ (r16 & 3)) * 8;        // swizzled granule offset for ds_read

    f32x4 acc[4][4];
#pragma unroll
    for (int mi = 0; mi < 4; ++mi)
#pragma unroll
        for (int ni = 0; ni < 4; ++ni)
            acc[mi][ni] = (f32x4){0.f, 0.f, 0.f, 0.f};

    // staging geometry: dest slot s (16B) = row*4 + p; source granule g = p ^ (row&3)
    int sr0 = tid >> 2,      sp = tid & 3;          // round 0 rows 0..63
    int sr1 = 64 + (tid >> 2);                      // round 1 rows 64..127
    int g0  = (sp ^ (sr0 & 3)) * 8;                 // element offset of source granule
    int g1  = (sp ^ (sr1 & 3)) * 8;

    auto stage = [&](int s) {
        int buf = s & 3;
        int k0 = s * 32;
        int seg = s >> 3;
        const ushort* Abase = (seg == 0) ? Ain : (seg == 1) ? Aout : X16p;
        int ka = k0 & 255;
        gload16(Abase + (size_t)(row0 + sr0) * 256 + ka + g0,
                (char*)&As[buf][0] + (size_t)(w * 64) * 16);
        gload16(Abase + (size_t)(row0 + sr1) * 256 + ka + g1,
                (char*)&As[buf][0] + 4096 + (size_t)(w * 64) * 16);
        gload16(wT + (size_t)(col0 + sr0) * 768 + k0 + g0,
                (char*)&Bs[buf][0] + (size_t)(w * 64) * 16);
        gload16(wT + (size_t)(col0 + sr1) * 768 + k0 + g1,
                (char*)&Bs[buf][0] + 4096 + (size_t)(w * 64) * 16);
    };

    stage(0); stage(1); stage(2);                   // 12 loads in flight / thread

    for (int kt = 0; kt < 24; ++kt) {
        // wait for stage kt only (loads complete in order; never drain to 0 mid-loop)
        if (kt < 22)       asm volatile("s_waitcnt vmcnt(8)" ::: "memory");
        else if (kt == 22) asm volatile("s_waitcnt vmcnt(4)" ::: "memory");
        else               asm volatile("s_waitcnt vmcnt(0)" ::: "memory");
        __builtin_amdgcn_s_barrier();
        asm volatile("" ::: "memory");
        if (kt + 3 < 24) stage(kt + 3);             // overwrites buf (kt-1)&3 — safe post-barrier

        int cur = kt & 3;
        bf16x8 af[4], bfr[4];
#pragma unroll
        for (int i = 0; i < 4; ++i) {
            af[i]  = *(const bf16x8*)&As[cur][(wr * 64 + i * 16 + r16) * 32 + kgS];
            bfr[i] = *(const bf16x8*)&Bs[cur][(wc * 64 + i * 16 + r16) * 32 + kgS];
        }
#pragma unroll
        for (int mi = 0; mi < 4; ++mi)
#pragma unroll
            for (int ni = 0; ni < 4; ++ni)
                acc[mi][ni] = __builtin_amdgcn_mfma_f32_16x16x32_bf16(af[mi], bfr[ni], acc[mi][ni], 0, 0, 0);
    }

#pragma unroll
    for (int mi = 0; mi < 4; ++mi) {
        int r = row0 + wr * 64 + mi * 16 + kg * 4;
#pragma unroll
        for (int ni = 0; ni < 4; ++ni) {
            int c = col0 + wc * 64 + ni * 16 + r16;
#pragma unroll
            for (int j = 0; j < 4; ++j) {
                int rr = r + j;
                if (rr < N_ENT) C[(size_t)rr * 256 + c] = acc[mi][ni][j];
            }
        }
    }

    // BN raw partial sums (pad rows are zeroed -> contribute 0)
#pragma unroll
    for (int ni = 0; ni < 4; ++ni) {
        float s = 0.f, ss = 0.f;
#pragma unroll
        for (int mi = 0; mi < 4; ++mi)
#pragma unroll
            for (int j = 0; j < 4; ++j) {
                float v = acc[mi][ni][j];
                s += v; ss += v * v;
            }
        s += __shfl_xor(s, 16); ss += __shfl_xor(ss, 16);
        s += __shfl_xor(s, 32); ss += __shfl_xor(ss, 32);
        if (kg == 0) {
            int c = col0 + wc * 64 + ni * 16 + r16;
            atomicAdd(&colsum[c], s);
            atomicAdd(&colsumsq[c], ss);
        }
    }
}

// ============ fallback GEMM (reg-staged, f32-x conversion inline) ============
__global__ __launch_bounds__(256) void fused_gemm_fb_kernel(
        const ushort* __restrict__ Ain, const ushort* __restrict__ Aout,
        const float* __restrict__ xf, const float* __restrict__ lrel,
        const ushort* __restrict__ wT, float* __restrict__ C) {
    __shared__ ushort As[2][128 * 40];
    __shared__ ushort Bs[2][128 * 40];
    int tid  = threadIdx.x;
    int row0 = blockIdx.x * 128;
    int col0 = blockIdx.y * 128;
    int srow = tid >> 1, hb = tid & 1;
    int w    = tid >> 6, lane = tid & 63;
    int wr   = w >> 1,  wc = w & 1;
    int r16  = lane & 15, kg = lane >> 4;

    f32x4 acc[4][4];
#pragma unroll
    for (int mi = 0; mi < 4; ++mi)
#pragma unroll
        for (int ni = 0; ni < 4; ++ni)
            acc[mi][ni] = (f32x4){0.f, 0.f, 0.f, 0.f};

    auto stage = [&](int kt, int buf) {
        int k0 = kt * 32;
        int seg = k0 >> 8;
        int kl  = (k0 & 255) + hb * 16;
        ushort* Ad = &As[buf][srow * 40 + hb * 16];
        if (seg < 2) {
            const ushort* src = (seg ? Aout : Ain) + (size_t)(row0 + srow) * 256 + kl;
            *(us8*)Ad       = *(const us8*)src;
            *(us8*)(Ad + 8) = *(const us8*)(src + 8);
        } else {
            int gr = row0 + srow;
            us8 pa, pb;
            if (gr < N_ENT) {
                const float* src = xf + (size_t)gr * 256 + kl;
                const float* ls  = lrel + kl;
#pragma unroll
                for (int j = 0; j < 8; ++j) {
                    pa[j] = (short)f2b(src[j] * ls[j]);
                    pb[j] = (short)f2b(src[8 + j] * ls[8 + j]);
                }
            } else {
#pragma unroll
                for (int j = 0; j < 8; ++j) { pa[j] = 0; pb[j] = 0; }
            }
            *(us8*)Ad       = pa;
            *(us8*)(Ad + 8) = pb;
        }
        ushort* Bd = &Bs[buf][srow * 40 + hb * 16];
        const ushort* bsrc = wT + (size_t)(col0 + srow) * 768 + k0 + hb * 16;
        *(us8*)Bd       = *(const us8*)bsrc;
        *(us8*)(Bd + 8) = *(const us8*)(bsrc + 8);
    };

    stage(0, 0);
    __syncthreads();
    for (int kt = 0; kt < 24; ++kt) {
        int cur = kt & 1;
        if (kt + 1 < 24) stage(kt + 1, cur ^ 1);
        const ushort* Ab = &As[cur][(wr * 64 + r16) * 40 + kg * 8];
        const ushort* Bb = &Bs[cur][(wc * 64 + r16) * 40 + kg * 8];
        bf16x8 af[4], bfr[4];
#pragma unroll
        for (int i = 0; i < 4; ++i) {
            af[i]  = *(const bf16x8*)(Ab + i * 640);
            bfr[i] = *(const bf16x8*)(Bb + i * 640);
        }
#pragma unroll
        for (int mi = 0; mi < 4; ++mi)
#pragma unroll
            for (int ni = 0; ni < 4; ++ni)
                acc[mi][ni] = __builtin_amdgcn_mfma_f32_16x16x32_bf16(af[mi], bfr[ni], acc[mi][ni], 0, 0, 0);
        __syncthreads();
    }

#pragma unroll
    for (int mi = 0; mi < 4; ++mi) {
        int r = row0 + wr * 64 + mi * 16 + kg * 4;
#pragma unroll
        for (int ni = 0; ni < 4; ++ni) {
            int c = col0 + wc * 64 + ni * 16 + r16;
#pragma unroll
            for (int j = 0; j < 4; ++j) {
                int rr = r + j;
                if (rr < N_ENT) C[(size_t)rr * 256 + c] = acc[mi][ni][j];
            }
        }
    }
}

// ---------------- BatchNorm ----------------
__global__ __launch_bounds__(256) void bn_stats_kernel(
        const float* __restrict__ out, const float* __restrict__ bias,
        float* __restrict__ colsum, float* __restrict__ colsumsq) {
    int c  = threadIdx.x;
    int r0 = blockIdx.x * 64;
    float b = bias[c];
    float s = 0.f, sq = 0.f;
    int rend = min(r0 + 64, N_ENT);
    for (int r = r0; r < rend; ++r) {
        float v = out[(size_t)r * 256 + c] * (1.f / 3.f) + b;
        s += v; sq += v * v;
    }
    atomicAdd(&colsum[c], s);
    atomicAdd(&colsumsq[c], sq);
}

template<bool RAW>
__global__ void bn_finalize_kernel(const float* __restrict__ colsum, const float* __restrict__ colsumsq,
                                   const float* __restrict__ bias, const float* __restrict__ gamma,
                                   const float* __restrict__ beta,
                                   float* __restrict__ colA, float* __restrict__ colB) {
    int c = threadIdx.x;
    float invN = 1.f / N_ENT;
    float mean, var;
    if (RAW) {
        float Er  = colsum[c] * invN;
        float Er2 = colsumsq[c] * invN;
        float b = bias[c];
        mean = Er * (1.f / 3.f) + b;
        var  = Er2 * (1.f / 9.f) + 2.f * b * Er * (1.f / 3.f) + b * b - mean * mean;
    } else {
        mean = colsum[c] * invN;
        var  = colsumsq[c] * invN - mean * mean;
    }
    float sc = rsqrtf(var + BN_EPS) * gamma[c];
    colA[c] = sc * (1.f / 3.f);
    colB[c] = (bias[c] - mean) * sc + beta[c];
}

__global__ __launch_bounds__(256) void bn_apply_kernel(
        float* __restrict__ out, const float* __restrict__ colA, const float* __restrict__ colB) {
    size_t i4 = (size_t)blockIdx.x * 256 + threadIdx.x;
    float4 v = ((const float4*)out)[i4];
    int c4 = (int)(i4 & 63) * 4;
    v.x = v.x * colA[c4 + 0] + colB[c4 + 0];
    v.y = v.y * colA[c4 + 1] + colB[c4 + 1];
    v.z = v.z * colA[c4 + 2] + colB[c4 + 2];
    v.w = v.w * colA[c4 + 3] + colB[c4 + 3];
    ((float4*)out)[i4] = v;
}

__global__ __launch_bounds__(256) void relgemm_kernel(
        const float* __restrict__ rel, const float* __restrict__ w, float* __restrict__ out) {
    int r = blockIdx.x;
    int c = threadIdx.x;
    float acc = 0.f;
    for (int k = 0; k < 256; ++k)
        acc = fmaf(rel[r * 256 + k], w[k * 256 + c], acc);
    out[r * 256 + c] = acc;
}

extern "C" void kernel_launch(void* const* d_in, const int* in_sizes, int n_in,
                              void* d_out, int out_size, void* d_ws, size_t ws_size,
                              hipStream_t stream) {
    const float* x        = (const float*)d_in[0];
    const int*   ei       = (const int*)d_in[1];
    const int*   et       = (const int*)d_in[2];
    const float* rel      = (const float*)d_in[3];
    const float* w_loop   = (const float*)d_in[4];
    const float* w_in     = (const float*)d_in[5];
    const float* w_out    = (const float*)d_in[6];
    const float* w_rel    = (const float*)d_in[7];
    const float* loop_rel = (const float*)d_in[8];
    const float* bias     = (const float*)d_in[9];
    const float* gamma    = (const float*)d_in[10];
    const float* beta     = (const float*)d_in[11];

    float* out     = (float*)d_out;
    float* rel_out = out + (size_t)N_ENT * D;
    const int* colidx = ei + NE2;

    // ---- workspace layout (full path) ----
    char* ws = (char*)d_ws;
    size_t off = 0;
    ushort* agg_in16  = (ushort*)(ws + off); off += (size_t)MPAD * D * 2;
    ushort* agg_out16 = (ushort*)(ws + off); off += (size_t)MPAD * D * 2;
    int* rp_in   = (int*)(ws + off); off += 400416;
    int* rp_out  = (int*)(ws + off); off += 400416;
    float* dv_in  = (float*)(ws + off); off += 400416;
    float* dv_out = (float*)(ws + off); off += 400416;
    uint2* el2_in  = (uint2*)(ws + off); off += (size_t)EHALF * 8;
    uint2* el2_out = (uint2*)(ws + off); off += (size_t)EHALF * 8;
    ushort* wT  = (ushort*)(ws + off); off += 768 * 256 * 2;
    float* stats = (float*)(ws + off); off += 8192;
    ushort* x16   = (ushort*)(ws + off); off += (size_t)MPAD * D * 2;
    ushort* rel16 = (ushort*)(ws + off); off += (size_t)NREL * D * 2;
    size_t needed_full = off;

    float* colsum = stats, *colsumsq = stats + 256;
    float* colA = stats + 512, *colB = stats + 768;
    int* bsum = (int*)(stats + 1024);
    int* cnt_in  = (int*)agg_in16;            // dead before agg written
    int* cnt_out = cnt_in + 100004;

    if (ws_size >= needed_full) {
        // ======== full path ========
        hipMemsetAsync(cnt_in, 0, 2 * 100004 * 4, stream);

        hist_kernel<<<(NE2 + 255) / 256, 256, 0, stream>>>(ei, cnt_in, cnt_out);
        scan1_kernel<<<dim3(98, 2), 256, 0, stream>>>(cnt_in, cnt_out, rp_in, rp_out, dv_in, dv_out, bsum);
        scan2_kernel<<<1, 256, 0, stream>>>(bsum, stats);
        scan3_kernel<<<dim3(98, 2), 256, 0, stream>>>(rp_in, rp_out, cnt_in, cnt_out, bsum);
        scatterp2_kernel<<<(NE2 + 255) / 256, 256, 0, stream>>>(ei, et, dv_in, dv_out,
                                                                cnt_in, cnt_out, el2_in, el2_out);
        prep_kernel<<<PB_PADS, 256, 0, stream>>>(x, rel, w_in, w_out, w_loop, loop_rel, w_rel,
                                                 x16, rel16, wT, rel_out, agg_in16, agg_out16);

        agg2_kernel<<<dim3((N_ENT * 64 + 255) / 256, 2), 256, 0, stream>>>(
            rp_in, el2_in, agg_in16, rp_out, el2_out, agg_out16, x16, rel16);

        fused_gemm3_kernel<<<dim3(MPAD / 128, 2), 256, 0, stream>>>(
            agg_in16, agg_out16, x16, wT, out, colsum, colsumsq);

        bn_finalize_kernel<true><<<1, 256, 0, stream>>>(colsum, colsumsq, bias, gamma, beta, colA, colB);
        bn_apply_kernel<<<(N_ENT * 64) / 256, 256, 0, stream>>>(out, colA, colB);
    } else {
        // ======== mid fallback: f32 gathers, separate bn_stats ========
        int* el_in  = (int*)el2_in;
        int* el_out = el_in + EHALF;
        hipMemsetAsync(cnt_in, 0, 2 * 100004 * 4, stream);
        hist_kernel<<<(NE2 + 255) / 256, 256, 0, stream>>>(ei, cnt_in, cnt_out);
        scan1_kernel<<<dim3(98, 2), 256, 0, stream>>>(cnt_in, cnt_out, rp_in, rp_out, dv_in, dv_out, bsum);
        scan2_kernel<<<1, 256, 0, stream>>>(bsum, stats);
        scan3_kernel<<<dim3(98, 2), 256, 0, stream>>>(rp_in, rp_out, cnt_in, cnt_out, bsum);
        scatter_kernel<<<(NE2 + 255) / 256, 256, 0, stream>>>(ei, cnt_in, cnt_out, el_in, el_out);
        wconv_kernel<<<256, 256, 0, stream>>>(w_in, w_out, w_loop, wT);

        agg_csr16_kernel<<<(N_ENT * 64 + 255) / 256, 256, 0, stream>>>(
            rp_in, el_in, colidx, et, dv_in, x, rel, agg_in16);
        agg_csr16_kernel<<<(N_ENT * 64 + 255) / 256, 256, 0, stream>>>(
            rp_out, el_out, colidx, et, dv_out, x, rel, agg_out16);

        fused_gemm_fb_kernel<<<dim3(MPAD / 128, 2), 256, 0, stream>>>(
            agg_in16, agg_out16, x, loop_rel, wT, out);

        bn_stats_kernel<<<(N_ENT + 63) / 64, 256, 0, stream>>>(out, bias, colsum, colsumsq);
        bn_finalize_kernel<false><<<1, 256, 0, stream>>>(colsum, colsumsq, bias, gamma, beta, colA, colB);
        bn_apply_kernel<<<(N_ENT * 64) / 256, 256, 0, stream>>>(out, colA, colB);
        relgemm_kernel<<<NREL, 256, 0, stream>>>(rel, w_rel, rel_out);
    }
}